// Round 3
// baseline (242.092 us; speedup 1.0000x reference)
//
#include <hip/hip_runtime.h>
#include <climits>

// Problem constants (fixed by the reference): B=8192 rows, D=512 features.
#define NB 8192
#define ND 512

// Straggler resolution:
//   wina_k: cols [64, 64+WCHUNKS*64) = [64,1088), up to WTILES*32 stragglers/z
//   tail_k: cols [64, NB) for the survivors (expected ~8/z after wina)
#define WCHUNKS 16
#define WTILES 8
#define TCHUNKS ((NB - 64) / 64)   // 127

// ===========================================================================
// Fast path: stats -> band -> wina -> tail -> final through d_ws.
// ws layout (floats): rnImg rnTxt rnCr dgSim dgCr mgCr [6*NB]
//            (ints):  negIdx [4*NB], stragCnt [16], stragList [4*NB]
// ===========================================================================

// Per-row stats + workspace init. 16 threads/row, 16 rows/block, 512 blocks.
__global__ __launch_bounds__(256) void stats_k(
        const float* __restrict__ img, const float* __restrict__ txt,
        const float* __restrict__ cr, const float* __restrict__ margin,
        const int* __restrict__ flagp,
        float* rnImg, float* rnTxt, float* rnCr,
        float* dgSim, float* dgCr, float* mgCr,
        int* negIdx, int* stragCnt, float* out) {
    int tid = threadIdx.x, bid = blockIdx.x;
    int g = bid * 256 + tid;
    if (g < 4 * NB) negIdx[g] = INT_MAX;
    if (bid == 0 && tid < 8) stragCnt[tid] = 0;
    if (bid == 0 && tid == 0) out[0] = 0.0f;

    int r = bid * 16 + (tid >> 4);
    int q = tid & 15;
    const float4* iv = (const float4*)(img + (size_t)r * ND);
    const float4* tv = (const float4*)(txt + (size_t)r * ND);
    const float4* cv = (const float4*)(cr  + (size_t)r * ND);
    float sii = 0, stt = 0, scc = 0, sit = 0, sic = 0;
    #pragma unroll
    for (int i = 0; i < 8; ++i) {                 // lane-contiguous: coalesced
        int k = q + i * 16;
        float4 x = iv[k], y = tv[k], w = cv[k];
        sii += x.x*x.x + x.y*x.y + x.z*x.z + x.w*x.w;
        stt += y.x*y.x + y.y*y.y + y.z*y.z + y.w*y.w;
        scc += w.x*w.x + w.y*w.y + w.z*w.z + w.w*w.w;
        sit += x.x*y.x + x.y*y.y + x.z*y.z + x.w*y.w;
        sic += x.x*w.x + x.y*w.y + x.z*w.z + x.w*w.w;
    }
    #pragma unroll
    for (int off = 1; off < 16; off <<= 1) {
        sii += __shfl_xor(sii, off); stt += __shfl_xor(stt, off);
        scc += __shfl_xor(scc, off); sit += __shfl_xor(sit, off);
        sic += __shfl_xor(sic, off);
    }
    if (q == 0) {
        float rnI = 1.0f / (sqrtf(sii) + 1e-8f);
        float rnT = 1.0f / (sqrtf(stt) + 1e-8f);
        float rnC = 1.0f / (sqrtf(scc) + 1e-8f);
        float ds = sit * rnI * rnT;
        float dc = sic * rnI * rnC;
        float m  = margin[r];
        float mcr = flagp[0] ? (fminf(fabsf(dc) / fabsf(ds), 1.0f) + 1.0f) * m * 0.5f
                             : m * 0.5f;
        rnImg[r] = rnI; rnTxt[r] = rnT; rnCr[r] = rnC;
        dgSim[r] = ds;  dgCr[r]  = dc;  mgCr[r] = mcr;
    }
}

__device__ inline void pass_arrays(int z,
        const float* img, const float* txt, const float* cr,
        const float* rnImg, const float* rnTxt, const float* rnCr,
        const float* dgSim, const float* dgCr,
        const float* margin, const float* mgCr,
        const float*& A, const float*& B, const float*& rnA, const float*& rnB,
        const float*& dgA, const float*& mgA) {
    if (z == 0)      { A = img; B = txt; rnA = rnImg; rnB = rnTxt; dgA = dgSim; mgA = margin; }
    else if (z == 1) { A = txt; B = img; rnA = rnTxt; rnB = rnImg; dgA = dgSim; mgA = margin; }
    else if (z == 2) { A = img; B = cr;  rnA = rnImg; rnB = rnCr;  dgA = dgCr;  mgA = mgCr;   }
    else             { A = cr;  B = img; rnA = rnCr;  rnB = rnImg; dgA = dgCr;  mgA = mgCr;   }
}

// 32x64xK=512 fp32 tile. LDS padded (+4) so staging writes are only 2-way
// bank-aliased (free) instead of 4-way; reads stay 16B-aligned vector loads.
// GATHER=false: A rows a0..a0+31 contiguous. GATHER=true: A rows from aRow[].
template <bool GATHER>
__device__ __forceinline__ void gemm32x64(
        const float* __restrict__ A, const float* __restrict__ B,
        int a0, const int* aRow, int c0,
        float (&As)[16][36], float (&Bs)[16][68],
        float (&acc)[2][4], int tid) {
    const int ty2 = (tid >> 4) * 2, tx4 = (tid & 15) * 4;
    const int lrow = tid >> 2, lk4 = (tid & 3) * 4;
    const bool doA = tid < 128;
    const int arow = GATHER ? (doA ? aRow[lrow] : 0) : (a0 + (lrow & 31));
    float4 va, vb;
    if (doA) va = *(const float4*)(A + (size_t)arow * ND + lk4);
    vb = *(const float4*)(B + (size_t)(c0 + lrow) * ND + lk4);
    for (int kc = 0; kc < ND; kc += 16) {
        __syncthreads();                       // prior compute done
        if (doA) {
            As[lk4 + 0][lrow] = va.x; As[lk4 + 1][lrow] = va.y;
            As[lk4 + 2][lrow] = va.z; As[lk4 + 3][lrow] = va.w;
        }
        Bs[lk4 + 0][lrow] = vb.x; Bs[lk4 + 1][lrow] = vb.y;
        Bs[lk4 + 2][lrow] = vb.z; Bs[lk4 + 3][lrow] = vb.w;
        if (kc + 16 < ND) {                    // software-pipelined prefetch
            if (doA) va = *(const float4*)(A + (size_t)arow * ND + kc + 16 + lk4);
            vb = *(const float4*)(B + (size_t)(c0 + lrow) * ND + kc + 16 + lk4);
        }
        __syncthreads();
        #pragma unroll
        for (int k = 0; k < 16; ++k) {
            float2 av = *(const float2*)&As[k][ty2];
            float4 bv = *(const float4*)&Bs[k][tx4];
            #pragma unroll
            for (int i = 0; i < 2; ++i) {
                float ai = i ? av.y : av.x;
                acc[i][0] = fmaf(ai, bv.x, acc[i][0]);
                acc[i][1] = fmaf(ai, bv.y, acc[i][1]);
                acc[i][2] = fmaf(ai, bv.z, acc[i][2]);
                acc[i][3] = fmaf(ai, bv.w, acc[i][3]);
            }
        }
    }
}

// Band: cols [0,64) for 32 anchors/block (1024 blocks -> 4 blocks/CU).
__global__ __launch_bounds__(256) void band_k(
        const float* __restrict__ img, const float* __restrict__ txt,
        const float* __restrict__ cr, const int* __restrict__ labels,
        const int* __restrict__ flagp, const float* __restrict__ margin,
        const float* __restrict__ betap,
        const float* rnImg, const float* rnTxt, const float* rnCr,
        const float* dgSim, const float* dgCr, const float* mgCr,
        int* stragCnt, int* stragList, float* out) {
    __shared__ __align__(16) float As[16][36];
    __shared__ __align__(16) float Bs[16][68];
    __shared__ float aRn[32], aDg[32], aMg[32], colRn[64];
    __shared__ int   aLab[32], colLab[64], resIdx[32];
    __shared__ float blockAcc;

    const int tid = threadIdx.x, z = blockIdx.y, a0 = blockIdx.x * 32;
    const int flag = flagp[0];
    const float *A, *B, *rnA, *rnB, *dgA, *mgA;
    pass_arrays(z, img, txt, cr, rnImg, rnTxt, rnCr, dgSim, dgCr, margin, mgCr,
                A, B, rnA, rnB, dgA, mgA);

    if (tid < 32) {
        int a = a0 + tid;
        float mg = mgA[a];
        aRn[tid] = rnA[a]; aDg[tid] = dgA[a]; aMg[tid] = mg;
        aLab[tid] = labels[a];
        resIdx[tid] = (flag && mg < 0.16f) ? -1 : INT_MAX;
    }
    if (tid < 64) { colRn[tid] = rnB[tid]; colLab[tid] = labels[tid]; }
    if (tid == 0) blockAcc = 0.0f;
    __syncthreads();

    float acc[2][4] = {};
    gemm32x64<false>(A, B, a0, nullptr, 0, As, Bs, acc, tid);
    __syncthreads();

    const int ty2 = (tid >> 4) * 2, tx4 = (tid & 15) * 4;
    // predicate pass: first valid (min col) via atomicMin
    #pragma unroll
    for (int i = 0; i < 2; ++i) {
        int r = ty2 + i;
        float mgv = aMg[r];
        if (flag && mgv < 0.16f) continue;     // pre-resolved: contributes 0
        float dg = aDg[r], rna = aRn[r];
        int la = aLab[r];
        #pragma unroll
        for (int j = 0; j < 4; ++j) {
            int c = tx4 + j;
            if (colLab[c] == la) continue;
            float lm = acc[i][j] * rna * colRn[c] - dg + mgv;
            if (lm > 0.0f && lm < mgv) atomicMin(&resIdx[r], c);
        }
    }
    __syncthreads();

    // winner pass: unique owner thread of the winning column adds lm
    #pragma unroll
    for (int i = 0; i < 2; ++i) {
        int r = ty2 + i;
        int w = resIdx[r];
        if (w < 0 || w == INT_MAX) continue;
        int c = w - tx4;
        if (c < 0 || c > 3) continue;
        float lm = acc[i][c] * aRn[r] * colRn[w] - aDg[r] + aMg[r];
        atomicAdd(&blockAcc, lm);
    }
    __syncthreads();

    if (tid < 32 && resIdx[tid] == INT_MAX) {  // unresolved -> global straggler
        int pos = atomicAdd(&stragCnt[z], 1);
        stragList[z * NB + pos] = a0 + tid;
    }
    if (tid == 0 && blockAcc != 0.0f) {
        float scale = (z >= 2) ? betap[0] : 1.0f;
        atomicAdd(out, blockAcc * scale);
    }
}

// wina: gathered 32-straggler tiles x 64-col chunks over [64,1088).
__global__ __launch_bounds__(256) void wina_k(
        const float* __restrict__ img, const float* __restrict__ txt,
        const float* __restrict__ cr, const int* __restrict__ labels,
        const float* __restrict__ margin,
        const float* rnImg, const float* rnTxt, const float* rnCr,
        const float* dgSim, const float* dgCr, const float* mgCr,
        const int* stragCnt, const int* stragList, int* negIdx) {
    __shared__ __align__(16) float As[16][36];
    __shared__ __align__(16) float Bs[16][68];
    __shared__ float aRn[32], aDg[32], aMg[32], colRn[64];
    __shared__ int   aId[32], aRow[32], aLab[32], colLab[64];

    const int tid = threadIdx.x, z = blockIdx.y;
    const int chunk = blockIdx.x & (WCHUNKS - 1);
    const int t     = blockIdx.x / WCHUNKS;
    const int cnt = stragCnt[z];
    if (t * 32 >= cnt) return;                 // uniform: no anchors here
    const int c0 = 64 + chunk * 64;

    const float *A, *B, *rnA, *rnB, *dgA, *mgA;
    pass_arrays(z, img, txt, cr, rnImg, rnTxt, rnCr, dgSim, dgCr, margin, mgCr,
                A, B, rnA, rnB, dgA, mgA);

    if (tid < 32) {
        int s = t * 32 + tid;
        int a = (s < cnt) ? stragList[z * NB + s] : -1;
        int ar = (a >= 0) ? a : 0;             // dummy row for padding lanes
        aId[tid] = a; aRow[tid] = ar;
        aRn[tid] = rnA[ar]; aDg[tid] = dgA[ar]; aMg[tid] = mgA[ar];
        aLab[tid] = labels[ar];
    }
    if (tid < 64) { colRn[tid] = rnB[c0 + tid]; colLab[tid] = labels[c0 + tid]; }
    __syncthreads();

    float acc[2][4] = {};
    gemm32x64<true>(A, B, 0, aRow, c0, As, Bs, acc, tid);
    __syncthreads();

    const int ty2 = (tid >> 4) * 2, tx4 = (tid & 15) * 4;
    #pragma unroll
    for (int i = 0; i < 2; ++i) {
        int r = ty2 + i;
        int a = aId[r];
        if (a < 0) continue;
        float dg = aDg[r], mgv = aMg[r], rna = aRn[r];
        int la = aLab[r];
        #pragma unroll
        for (int j = 0; j < 4; ++j) {
            int c = tx4 + j;
            if (colLab[c] == la) continue;
            float lm = acc[i][j] * rna * colRn[c] - dg + mgv;
            if (lm > 0.0f && lm < mgv) atomicMin(&negIdx[z * NB + a], c0 + c);
        }
    }
}

__device__ inline float dot8(const float4& a0, const float4& a1,
                             const float4& b0, const float4& b1) {
    return a0.x*b0.x + a0.y*b0.y + a0.z*b0.z + a0.w*b0.w
         + a1.x*b1.x + a1.y*b1.y + a1.z*b1.z + a1.w*b1.w;
}

// tail: survivors of wina (negIdx still INT_MAX) swept over cols [64,NB) in
// 64-col chunks, survivor A-rows staged in LDS (groups of 8), coalesced
// wave-batched dots + shuffle reduce. Per-block cost ~128KB of B loads.
__global__ __launch_bounds__(256) void tail_k(
        const float* __restrict__ img, const float* __restrict__ txt,
        const float* __restrict__ cr, const int* __restrict__ labels,
        const float* __restrict__ margin,
        const float* rnImg, const float* rnTxt, const float* rnCr,
        const float* dgSim, const float* dgCr, const float* mgCr,
        const int* stragCnt, const int* stragList, int* negIdx) {
    __shared__ __align__(16) float Aload[8][ND];   // 16 KB
    __shared__ float sRn[8], sDg[8], sMg[8];
    __shared__ int   sLab[8], sAid[8];
    __shared__ float colRn_s[64];
    __shared__ int   colLab_s[64];
    __shared__ int   sSurv[256];
    __shared__ int   sNa;

    const int tid = threadIdx.x, z = blockIdx.y;
    const int c0 = 64 + blockIdx.x * 64;
    const int cnt = stragCnt[z];
    if (cnt == 0) return;

    const float *A, *B, *rnA, *rnB, *dgA, *mgA;
    pass_arrays(z, img, txt, cr, rnImg, rnTxt, rnCr, dgSim, dgCr, margin, mgCr,
                A, B, rnA, rnB, dgA, mgA);

    // survivor compaction (order irrelevant: result is a global min)
    if (tid == 0) sNa = 0;
    __syncthreads();
    for (int s = tid; s < cnt; s += 256) {
        int a = stragList[z * NB + s];
        if (negIdx[z * NB + a] == INT_MAX) {
            int p = atomicAdd(&sNa, 1);
            if (p < 256) sSurv[p] = a;
        }
    }
    __syncthreads();
    const int na = min(sNa, 256);
    if (na == 0) return;

    if (tid < 64) { colRn_s[tid] = rnB[c0 + tid]; colLab_s[tid] = labels[c0 + tid]; }

    const int wv = tid >> 6, lane = tid & 63;

    for (int g0 = 0; g0 < na; g0 += 8) {
        const int gn = min(8, na - g0);
        __syncthreads();                       // protect Aload/params reuse
        if (tid < 8) {
            int s = g0 + ((tid < gn) ? tid : 0);
            int a = sSurv[s];
            sAid[tid] = (tid < gn) ? a : -1;
            sRn[tid] = rnA[a]; sDg[tid] = dgA[a]; sMg[tid] = mgA[a];
            sLab[tid] = labels[a];
        }
        #pragma unroll
        for (int m = 0; m < 4; ++m) {          // stage 8 survivor rows: 1024 f4
            int idx = tid + m * 256;
            int row = idx >> 7, f4 = idx & 127;
            int a = sSurv[g0 + ((row < gn) ? row : 0)];
            *(float4*)&Aload[row][f4 * 4] =
                *(const float4*)(A + (size_t)a * ND + f4 * 4);
        }
        __syncthreads();

        // each wave: 16 cols, in batches of 4 (B loads shared across survivors)
        for (int cb = 0; cb < 16; cb += 4) {
            const int cc0 = wv * 16 + cb;
            float4 b0[4], b1[4];
            #pragma unroll
            for (int q = 0; q < 4; ++q) {
                const float4* Bv = (const float4*)(B + (size_t)(c0 + cc0 + q) * ND);
                b0[q] = Bv[lane]; b1[q] = Bv[lane + 64];
            }
            #pragma unroll
            for (int s = 0; s < 8; ++s) {
                float4 a0v = *(const float4*)&Aload[s][lane * 4];
                float4 a1v = *(const float4*)&Aload[s][(lane + 64) * 4];
                float d0 = dot8(a0v, a1v, b0[0], b1[0]);
                float d1 = dot8(a0v, a1v, b0[1], b1[1]);
                float d2 = dot8(a0v, a1v, b0[2], b1[2]);
                float d3 = dot8(a0v, a1v, b0[3], b1[3]);
                #pragma unroll
                for (int off = 1; off < 64; off <<= 1) {
                    d0 += __shfl_xor(d0, off); d1 += __shfl_xor(d1, off);
                    d2 += __shfl_xor(d2, off); d3 += __shfl_xor(d3, off);
                }
                if (lane == 0) {
                    int aid = sAid[s];
                    if (aid >= 0) {
                        float rn = sRn[s], dg = sDg[s], mg = sMg[s];
                        int lb = sLab[s];
                        float dv[4] = {d0, d1, d2, d3};
                        #pragma unroll
                        for (int q = 0; q < 4; ++q) {
                            int cc = cc0 + q;
                            if (colLab_s[cc] != lb) {
                                float lm = dv[q] * rn * colRn_s[cc] - dg + mg;
                                if (lm > 0.0f && lm < mg)
                                    atomicMin(&negIdx[z * NB + aid], c0 + cc);
                            }
                        }
                    }
                }
            }
        }
    }
}

// Recompute winning sim value per straggler, block-reduce, accumulate.
__global__ __launch_bounds__(256) void final_k(
        const float* __restrict__ img, const float* __restrict__ txt,
        const float* __restrict__ cr,
        const float* rnImg, const float* rnTxt, const float* rnCr,
        const float* dgSim, const float* dgCr,
        const float* __restrict__ margin, const float* mgCr,
        const float* __restrict__ betap,
        const int* stragCnt, const int* stragList, const int* negIdx,
        float* out) {
    __shared__ float s4[4];
    const int tid = threadIdx.x, z = blockIdx.y;
    const float *A, *B, *rnA, *rnB, *dgA, *mgA;
    pass_arrays(z, img, txt, cr, rnImg, rnTxt, rnCr, dgSim, dgCr, margin, mgCr,
                A, B, rnA, rnB, dgA, mgA);
    int t = blockIdx.x * 256 + tid;
    float contrib = 0.0f;
    if (t < stragCnt[z]) {
        int a = stragList[z * NB + t];
        int idx = negIdx[z * NB + a];
        if (idx != INT_MAX) {
            const float4* Av = (const float4*)(A + (size_t)a   * ND);
            const float4* Bv = (const float4*)(B + (size_t)idx * ND);
            float d = 0.0f;
            #pragma unroll 8
            for (int i = 0; i < ND / 4; ++i) {
                float4 x = Av[i], y = Bv[i];
                d += x.x*y.x + x.y*y.y + x.z*y.z + x.w*y.w;
            }
            float lm = d * rnA[a] * rnB[idx] - dgA[a] + mgA[a];
            contrib = fmaxf(lm, 0.0f);
        }
    }
    #pragma unroll
    for (int off = 32; off; off >>= 1) contrib += __shfl_xor(contrib, off);
    if ((tid & 63) == 0) s4[tid >> 6] = contrib;
    __syncthreads();
    if (tid == 0) {
        float sum = s4[0] + s4[1] + s4[2] + s4[3];
        if (sum != 0.0f) atomicAdd(out, sum * ((z >= 2) ? betap[0] : 1.0f));
    }
}

// ===========================================================================
// Fallback path (no workspace) — the proven round-3 single-kernel version.
// ===========================================================================

__global__ __launch_bounds__(256) void zero_k(float* out, int n) {
    int g = blockIdx.x * 256 + threadIdx.x;
    if (g < n) out[g] = 0.0f;
}

template <int U>
__device__ void stragScan(const float* __restrict__ A, const float* __restrict__ B,
                          const int* __restrict__ labels, int a0, int u, int scol,
                          const int* sList, int g0,
                          const float* aRn, const float* aDg, const float* aMg,
                          const int* aLab, int* sMin8, int* doneMask,
                          float* blockAcc) {
    const int tid = threadIdx.x;
    float rn_s[U], dg_s[U], mg_s[U];
    int lab_s[U];
    const float4* Av[U];
    #pragma unroll
    for (int s = 0; s < U; ++s) {
        int slot = sList[g0 + (s < u ? s : 0)];
        rn_s[s] = aRn[slot]; dg_s[s] = aDg[slot]; mg_s[s] = aMg[slot];
        lab_s[s] = aLab[slot];
        Av[s] = (const float4*)(A + (size_t)(a0 + slot) * ND);
    }
    if (tid < U) sMin8[tid] = INT_MAX;
    if (tid == 0) *doneMask = 0;
    __syncthreads();
    for (int jb = scol; jb < NB; jb += 256) {
        int j = jb + tid;
        bool jv = (j < NB);
        int mask = *doneMask;
        float dot[U];
        #pragma unroll
        for (int s = 0; s < U; ++s) dot[s] = 0.0f;
        float ssq = 0.0f;
        if (jv) {
            const float4* Bv = (const float4*)(B + (size_t)j * ND);
            #pragma unroll 4
            for (int k4 = 0; k4 < ND / 4; ++k4) {
                float4 b = Bv[k4];
                ssq += b.x*b.x + b.y*b.y + b.z*b.z + b.w*b.w;
                #pragma unroll
                for (int s = 0; s < U; ++s) {
                    float4 a = Av[s][k4];
                    dot[s] += a.x*b.x + a.y*b.y + a.z*b.z + a.w*b.w;
                }
            }
        }
        float rnb = 1.0f / (sqrtf(ssq) + 1e-8f);
        int lj = jv ? labels[j] : -1;
        float lmv[U];
        #pragma unroll
        for (int s = 0; s < U; ++s) {
            lmv[s] = dot[s] * rn_s[s] * rnb - dg_s[s] + mg_s[s];
            if (jv && s < u && !((mask >> s) & 1) && lj != lab_s[s] &&
                lmv[s] > 0.0f && lmv[s] < mg_s[s])
                atomicMin(&sMin8[s], j);
        }
        __syncthreads();
        #pragma unroll
        for (int s = 0; s < U; ++s)
            if (jv && s < u && !((mask >> s) & 1) && sMin8[s] == j)
                atomicAdd(blockAcc, lmv[s]);
        __syncthreads();
        if (tid == 0) {
            int m2 = 0;
            for (int s = 0; s < u; ++s)
                if (sMin8[s] != INT_MAX) m2 |= (1 << s);
            *doneMask = m2;
        }
        __syncthreads();
        if (*doneMask == (1 << u) - 1) break;
    }
}

__global__ __launch_bounds__(256) void mine_k(const float* __restrict__ img,
                                              const float* __restrict__ txt,
                                              const float* __restrict__ cr,
                                              const int*   __restrict__ labels,
                                              const int*   __restrict__ flagp,
                                              const float* __restrict__ margin,
                                              const float* __restrict__ betap,
                                              float* __restrict__ out) {
    __shared__ __align__(16) float As[16][64];
    __shared__ __align__(16) float Bs[16][64];
    __shared__ float aRn[64], aDg[64], aMg[64];
    __shared__ int   aLab[64];
    __shared__ float colRn[64];
    __shared__ int   colLab[64];
    __shared__ int   resIdx[64], prevIdx[64];
    __shared__ int   cnt;
    __shared__ float blockAcc;
    __shared__ int   sList[64];
    __shared__ int   sCnt;
    __shared__ int   sMin8[8];
    __shared__ int   doneMask;

    const int tid  = threadIdx.x;
    const int z    = blockIdx.y;
    const int a0   = blockIdx.x * 64;
    const int flag = flagp[0];
    const float* A = (z == 1) ? txt : (z == 3) ? cr : img;
    const float* B = (z == 0) ? txt : (z == 2) ? cr : img;
    {
        int ar = tid >> 2, q = tid & 3;
        int a  = a0 + ar;
        const float4* iv = (const float4*)(img + (size_t)a * ND) + q * 32;
        const float4* tv = (const float4*)(txt + (size_t)a * ND) + q * 32;
        const float4* cv = (const float4*)(cr  + (size_t)a * ND) + q * 32;
        float sii = 0, stt = 0, scc = 0, sit = 0, sic = 0;
        #pragma unroll 4
        for (int i = 0; i < 32; ++i) {
            float4 x = iv[i], y = tv[i], w = cv[i];
            sii += x.x*x.x + x.y*x.y + x.z*x.z + x.w*x.w;
            stt += y.x*y.x + y.y*y.y + y.z*y.z + y.w*y.w;
            scc += w.x*w.x + w.y*w.y + w.z*w.z + w.w*w.w;
            sit += x.x*y.x + x.y*y.y + x.z*y.z + x.w*y.w;
            sic += x.x*w.x + x.y*w.y + x.z*w.z + x.w*w.w;
        }
        sii += __shfl_xor(sii, 1); sii += __shfl_xor(sii, 2);
        stt += __shfl_xor(stt, 1); stt += __shfl_xor(stt, 2);
        sit += __shfl_xor(sit, 1); sit += __shfl_xor(sit, 2);
        scc += __shfl_xor(scc, 1); scc += __shfl_xor(scc, 2);
        sic += __shfl_xor(sic, 1); sic += __shfl_xor(sic, 2);
        if (q == 0) {
            float rnI = 1.0f / (sqrtf(sii) + 1e-8f);
            float rnT = 1.0f / (sqrtf(stt) + 1e-8f);
            float ds  = sit * rnI * rnT;
            float m   = margin[a];
            float mg, rna, dgv;
            if (z >= 2) {
                float rnC = 1.0f / (sqrtf(scc) + 1e-8f);
                float dc  = sic * rnI * rnC;
                mg = flag ? (fminf(fabsf(dc) / fabsf(ds), 1.0f) + 1.0f) * m * 0.5f
                          : m * 0.5f;
                dgv = dc; rna = (z == 3) ? rnC : rnI;
            } else {
                mg = m; dgv = ds; rna = (z == 1) ? rnT : rnI;
            }
            aRn[ar] = rna; aDg[ar] = dgv; aMg[ar] = mg; aLab[ar] = labels[a];
            resIdx[ar] = (flag && mg < 0.16f) ? -1 : INT_MAX;
        }
        if (tid == 0) blockAcc = 0.0f;
    }
    __syncthreads();
    const int ty4  = (tid >> 4) * 4, tx4 = (tid & 15) * 4;
    const int lrow = tid >> 2,  lk4 = (tid & 3) * 4;
    int bandCols = 0, unresolved = 64;
    for (int jc = 0; jc < 2; ++jc) {
        int j0 = jc * 64;
        float acc[4][4];
        #pragma unroll
        for (int i = 0; i < 4; ++i)
            #pragma unroll
            for (int j = 0; j < 4; ++j) acc[i][j] = 0.0f;
        float bssq = 0.0f;
        for (int kc = 0; kc < ND; kc += 16) {
            __syncthreads();
            float4 va = *(const float4*)(A + (size_t)(a0 + lrow) * ND + kc + lk4);
            float4 vb = *(const float4*)(B + (size_t)(j0 + lrow) * ND + kc + lk4);
            As[lk4 + 0][lrow] = va.x; As[lk4 + 1][lrow] = va.y;
            As[lk4 + 2][lrow] = va.z; As[lk4 + 3][lrow] = va.w;
            Bs[lk4 + 0][lrow] = vb.x; Bs[lk4 + 1][lrow] = vb.y;
            Bs[lk4 + 2][lrow] = vb.z; Bs[lk4 + 3][lrow] = vb.w;
            bssq += vb.x*vb.x + vb.y*vb.y + vb.z*vb.z + vb.w*vb.w;
            __syncthreads();
            #pragma unroll
            for (int k = 0; k < 16; ++k) {
                float4 av = *(const float4*)&As[k][ty4];
                float4 bv = *(const float4*)&Bs[k][tx4];
                float ar[4] = {av.x, av.y, av.z, av.w};
                float br[4] = {bv.x, bv.y, bv.z, bv.w};
                #pragma unroll
                for (int i = 0; i < 4; ++i)
                    #pragma unroll
                    for (int j = 0; j < 4; ++j)
                        acc[i][j] = fmaf(ar[i], br[j], acc[i][j]);
            }
        }
        bssq += __shfl_xor(bssq, 1); bssq += __shfl_xor(bssq, 2);
        __syncthreads();
        if ((tid & 3) == 0) {
            colRn[lrow]  = 1.0f / (sqrtf(bssq) + 1e-8f);
            colLab[lrow] = labels[j0 + lrow];
        }
        if (tid < 64) prevIdx[tid] = resIdx[tid];
        __syncthreads();
        #pragma unroll
        for (int i = 0; i < 4; ++i) {
            int r = ty4 + i;
            if (prevIdx[r] != INT_MAX) continue;
            float dg = aDg[r], mgv = aMg[r], rna = aRn[r];
            int la = aLab[r];
            #pragma unroll
            for (int j = 0; j < 4; ++j) {
                int c = tx4 + j;
                if (colLab[c] == la) continue;
                float v  = acc[i][j] * rna * colRn[c];
                float lm = v - dg + mgv;
                if (lm > 0.0f && lm < mgv) atomicMin(&resIdx[r], j0 + c);
            }
        }
        __syncthreads();
        #pragma unroll
        for (int i = 0; i < 4; ++i) {
            int r = ty4 + i;
            if (prevIdx[r] != INT_MAX) continue;
            int w = resIdx[r];
            if (w == INT_MAX) continue;
            int c = w - j0 - tx4;
            if (c < 0 || c > 3) continue;
            float v  = acc[i][c] * aRn[r] * colRn[tx4 + c];
            float lm = v - aDg[r] + aMg[r];
            atomicAdd(&blockAcc, lm);
        }
        __syncthreads();
        if (tid == 0) cnt = 0;
        __syncthreads();
        if (tid < 64 && resIdx[tid] == INT_MAX) atomicAdd(&cnt, 1);
        __syncthreads();
        unresolved = cnt;
        bandCols = j0 + 64;
        __syncthreads();
        if (unresolved <= 8) break;
    }
    if (unresolved > 0) {
        if (tid == 0) sCnt = 0;
        __syncthreads();
        if (tid < 64 && resIdx[tid] == INT_MAX) {
            int pos = atomicAdd(&sCnt, 1);
            sList[pos] = tid;
        }
        __syncthreads();
        int total = sCnt;
        for (int g0 = 0; g0 < total; g0 += 8) {
            int u = min(8, total - g0);
            if (u == 1)      stragScan<1>(A, B, labels, a0, u, bandCols, sList, g0, aRn, aDg, aMg, aLab, sMin8, &doneMask, &blockAcc);
            else if (u == 2) stragScan<2>(A, B, labels, a0, u, bandCols, sList, g0, aRn, aDg, aMg, aLab, sMin8, &doneMask, &blockAcc);
            else if (u <= 4) stragScan<4>(A, B, labels, a0, u, bandCols, sList, g0, aRn, aDg, aMg, aLab, sMin8, &doneMask, &blockAcc);
            else             stragScan<8>(A, B, labels, a0, u, bandCols, sList, g0, aRn, aDg, aMg, aLab, sMin8, &doneMask, &blockAcc);
            __syncthreads();
        }
    }
    if (tid == 0 && blockAcc != 0.0f) {
        float scale = (z >= 2) ? betap[0] : 1.0f;
        atomicAdd(out, blockAcc * scale);
    }
}

// ===========================================================================

extern "C" void kernel_launch(void* const* d_in, const int* in_sizes, int n_in,
                              void* d_out, int out_size, void* d_ws, size_t ws_size,
                              hipStream_t stream) {
    const float* img    = (const float*)d_in[0];
    const float* txt    = (const float*)d_in[1];
    const float* cr     = (const float*)d_in[2];
    const int*   labels = (const int*)  d_in[3];
    const int*   flagp  = (const int*)  d_in[4];
    const float* marg   = (const float*)d_in[5];
    const float* betap  = (const float*)d_in[6];
    float* out = (float*)d_out;
    (void)in_sizes; (void)n_in;

    const size_t REQ = (size_t)(6 * NB) * 4 + (size_t)(4 * NB) * 4 + 64 +
                       (size_t)(4 * NB) * 4;
    if (ws_size >= REQ) {
        float* wf = (float*)d_ws;
        float* rnImg = wf + 0 * NB;
        float* rnTxt = wf + 1 * NB;
        float* rnCr  = wf + 2 * NB;
        float* dgSim = wf + 3 * NB;
        float* dgCr  = wf + 4 * NB;
        float* mgCr  = wf + 5 * NB;
        int* negIdx    = (int*)(wf + 6 * NB);
        int* stragCnt  = negIdx + 4 * NB;
        int* stragList = stragCnt + 16;

        stats_k<<<dim3(NB / 16),              dim3(256), 0, stream>>>(
            img, txt, cr, marg, flagp,
            rnImg, rnTxt, rnCr, dgSim, dgCr, mgCr, negIdx, stragCnt, out);
        band_k <<<dim3(NB / 32, 4),           dim3(256), 0, stream>>>(
            img, txt, cr, labels, flagp, marg, betap,
            rnImg, rnTxt, rnCr, dgSim, dgCr, mgCr, stragCnt, stragList, out);
        wina_k <<<dim3(WCHUNKS * WTILES, 4),  dim3(256), 0, stream>>>(
            img, txt, cr, labels, marg,
            rnImg, rnTxt, rnCr, dgSim, dgCr, mgCr,
            stragCnt, stragList, negIdx);
        tail_k <<<dim3(TCHUNKS, 4),           dim3(256), 0, stream>>>(
            img, txt, cr, labels, marg,
            rnImg, rnTxt, rnCr, dgSim, dgCr, mgCr,
            stragCnt, stragList, negIdx);
        final_k<<<dim3(NB / 256, 4),          dim3(256), 0, stream>>>(
            img, txt, cr, rnImg, rnTxt, rnCr, dgSim, dgCr, marg, mgCr, betap,
            stragCnt, stragList, negIdx, out);
    } else {
        zero_k<<<dim3((out_size + 255) / 256), dim3(256), 0, stream>>>(out, out_size);
        mine_k<<<dim3(NB / 64, 4), dim3(256), 0, stream>>>(img, txt, cr, labels,
                                                           flagp, marg, betap, out);
    }
}

// Round 4
// 227.061 us; speedup vs baseline: 1.0662x; 1.0662x over previous
//
#include <hip/hip_runtime.h>
#include <climits>

// Problem constants (fixed by the reference): B=8192 rows, D=512 features.
#define NB 8192
#define ND 512

// Straggler resolution:
//   wina_k: cols [64, 64+WCHUNKS*64) = [64,1088), up to WTILES*32 stragglers/z
//   tail_k: cols [64, NB) for the survivors (expected ~2/z after wina),
//           32-col chunks; skips [64,1088) unless wina capacity overflowed.
#define WCHUNKS 16
#define WTILES 8
#define TCHUNKS ((NB - 64) / 32)   // 254

// ===========================================================================
// Fast path: stats -> band2 -> wina -> tail -> final through d_ws.
// ws layout (floats): rnImg rnTxt rnCr dgSim dgCr mgCr [6*NB]
//            (ints):  negIdx [4*NB], stragCnt [16], stragList [4*NB]
// ===========================================================================

// Per-row stats + workspace init. 16 threads/row, 16 rows/block, 512 blocks.
__global__ __launch_bounds__(256) void stats_k(
        const float* __restrict__ img, const float* __restrict__ txt,
        const float* __restrict__ cr, const float* __restrict__ margin,
        const int* __restrict__ flagp,
        float* rnImg, float* rnTxt, float* rnCr,
        float* dgSim, float* dgCr, float* mgCr,
        int* negIdx, int* stragCnt, float* out) {
    int tid = threadIdx.x, bid = blockIdx.x;
    int g = bid * 256 + tid;
    if (g < 4 * NB) negIdx[g] = INT_MAX;
    if (bid == 0 && tid < 8) stragCnt[tid] = 0;
    if (bid == 0 && tid == 0) out[0] = 0.0f;

    int r = bid * 16 + (tid >> 4);
    int q = tid & 15;
    const float4* iv = (const float4*)(img + (size_t)r * ND);
    const float4* tv = (const float4*)(txt + (size_t)r * ND);
    const float4* cv = (const float4*)(cr  + (size_t)r * ND);
    float sii = 0, stt = 0, scc = 0, sit = 0, sic = 0;
    #pragma unroll
    for (int i = 0; i < 8; ++i) {                 // lane-contiguous: coalesced
        int k = q + i * 16;
        float4 x = iv[k], y = tv[k], w = cv[k];
        sii += x.x*x.x + x.y*x.y + x.z*x.z + x.w*x.w;
        stt += y.x*y.x + y.y*y.y + y.z*y.z + y.w*y.w;
        scc += w.x*w.x + w.y*w.y + w.z*w.z + w.w*w.w;
        sit += x.x*y.x + x.y*y.y + x.z*y.z + x.w*y.w;
        sic += x.x*w.x + x.y*w.y + x.z*w.z + x.w*w.w;
    }
    #pragma unroll
    for (int off = 1; off < 16; off <<= 1) {
        sii += __shfl_xor(sii, off); stt += __shfl_xor(stt, off);
        scc += __shfl_xor(scc, off); sit += __shfl_xor(sit, off);
        sic += __shfl_xor(sic, off);
    }
    if (q == 0) {
        float rnI = 1.0f / (sqrtf(sii) + 1e-8f);
        float rnT = 1.0f / (sqrtf(stt) + 1e-8f);
        float rnC = 1.0f / (sqrtf(scc) + 1e-8f);
        float ds = sit * rnI * rnT;
        float dc = sic * rnI * rnC;
        float m  = margin[r];
        float mcr = flagp[0] ? (fminf(fabsf(dc) / fabsf(ds), 1.0f) + 1.0f) * m * 0.5f
                             : m * 0.5f;
        rnImg[r] = rnI; rnTxt[r] = rnT; rnCr[r] = rnC;
        dgSim[r] = ds;  dgCr[r]  = dc;  mgCr[r] = mcr;
    }
}

__device__ inline void pass_arrays(int z,
        const float* img, const float* txt, const float* cr,
        const float* rnImg, const float* rnTxt, const float* rnCr,
        const float* dgSim, const float* dgCr,
        const float* margin, const float* mgCr,
        const float*& A, const float*& B, const float*& rnA, const float*& rnB,
        const float*& dgA, const float*& mgA) {
    if (z == 0)      { A = img; B = txt; rnA = rnImg; rnB = rnTxt; dgA = dgSim; mgA = margin; }
    else if (z == 1) { A = txt; B = img; rnA = rnTxt; rnB = rnImg; dgA = dgSim; mgA = margin; }
    else if (z == 2) { A = img; B = cr;  rnA = rnImg; rnB = rnCr;  dgA = dgCr;  mgA = mgCr;   }
    else             { A = cr;  B = img; rnA = rnCr;  rnB = rnImg; dgA = dgCr;  mgA = mgCr;   }
}

// ---------------------------------------------------------------------------
// band2: pair-merged band GEMM. blockIdx.y = pair:
//   pair 0: rows = img anchors (z0: vs txt cols, z2: vs cr cols) — shared rows
//   pair 1: cols = img[0:64]   (z1: txt anchors, z3: cr anchors) — shared cols
// One block: 64 anchors x 64 cols x 2 z's. 3 LDS tiles, 2 accumulators:
// per k, 3x ds_read_b128 feed 32 FMAs -> VALU-bound (vs LDS-bound R3 tile).
// ---------------------------------------------------------------------------
__global__ __launch_bounds__(256) void band2_k(
        const float* __restrict__ img, const float* __restrict__ txt,
        const float* __restrict__ cr, const int* __restrict__ labels,
        const int* __restrict__ flagp, const float* __restrict__ margin,
        const float* __restrict__ betap,
        const float* rnImg, const float* rnTxt, const float* rnCr,
        const float* dgSim, const float* dgCr, const float* mgCr,
        int* stragCnt, int* stragList, float* out) {
    __shared__ __align__(16) float T0[16][68];   // img tile
    __shared__ __align__(16) float T1[16][68];   // txt tile
    __shared__ __align__(16) float T2[16][68];   // cr tile
    __shared__ float aRn1[64], aDg1[64], aMg1[64];
    __shared__ float aRn2[64], aDg2[64], aMg2[64];
    __shared__ float cRn1[64], cRn2[64];
    __shared__ int   aLab[64], cLab[64], res1[64], res2[64];
    __shared__ float bAcc1, bAcc2;

    const int tid = threadIdx.x, pair = blockIdx.y, a0 = blockIdx.x * 64;
    const int flag = flagp[0];

    if (tid < 64) {
        int a = a0 + tid;
        aLab[tid] = labels[a];
        cLab[tid] = labels[tid];
        float m = margin[a], mc = mgCr[a];
        if (pair == 0) {
            float rn = rnImg[a];
            aRn1[tid] = rn;         aDg1[tid] = dgSim[a]; aMg1[tid] = m;
            aRn2[tid] = rn;         aDg2[tid] = dgCr[a];  aMg2[tid] = mc;
            cRn1[tid] = rnTxt[tid]; cRn2[tid] = rnCr[tid];
        } else {
            aRn1[tid] = rnTxt[a];   aDg1[tid] = dgSim[a]; aMg1[tid] = m;
            aRn2[tid] = rnCr[a];    aDg2[tid] = dgCr[a];  aMg2[tid] = mc;
            float ri = rnImg[tid];  cRn1[tid] = ri;       cRn2[tid] = ri;
        }
        res1[tid] = (flag && m  < 0.16f) ? -1 : INT_MAX;
        res2[tid] = (flag && mc < 0.16f) ? -1 : INT_MAX;
    }
    if (tid == 0) { bAcc1 = 0.0f; bAcc2 = 0.0f; }

    const int lrow = tid >> 2, lk4 = (tid & 3) * 4;
    const int rImg = pair ? lrow : (a0 + lrow);      // T0 source row (img)
    const int rTC  = pair ? (a0 + lrow) : lrow;      // T1/T2 source row (txt/cr)
    const float* p0 = img + (size_t)rImg * ND + lk4;
    const float* p1 = txt + (size_t)rTC  * ND + lk4;
    const float* p2 = cr  + (size_t)rTC  * ND + lk4;

    const int ty4 = (tid >> 4) * 4, tx4 = (tid & 15) * 4;
    float acc1[4][4] = {}, acc2[4][4] = {};

    float4 v0 = *(const float4*)p0;
    float4 v1 = *(const float4*)p1;
    float4 v2 = *(const float4*)p2;

    if (pair == 0) {
        for (int kc = 0; kc < ND; kc += 16) {
            __syncthreads();
            T0[lk4 + 0][lrow] = v0.x; T0[lk4 + 1][lrow] = v0.y;
            T0[lk4 + 2][lrow] = v0.z; T0[lk4 + 3][lrow] = v0.w;
            T1[lk4 + 0][lrow] = v1.x; T1[lk4 + 1][lrow] = v1.y;
            T1[lk4 + 2][lrow] = v1.z; T1[lk4 + 3][lrow] = v1.w;
            T2[lk4 + 0][lrow] = v2.x; T2[lk4 + 1][lrow] = v2.y;
            T2[lk4 + 2][lrow] = v2.z; T2[lk4 + 3][lrow] = v2.w;
            if (kc + 16 < ND) {
                v0 = *(const float4*)(p0 + kc + 16);
                v1 = *(const float4*)(p1 + kc + 16);
                v2 = *(const float4*)(p2 + kc + 16);
            }
            __syncthreads();
            #pragma unroll
            for (int k = 0; k < 16; ++k) {
                float4 rv = *(const float4*)&T0[k][ty4];   // shared rows (img)
                float4 c1 = *(const float4*)&T1[k][tx4];   // txt cols
                float4 c2 = *(const float4*)&T2[k][tx4];   // cr cols
                float rr[4] = {rv.x, rv.y, rv.z, rv.w};
                float b1[4] = {c1.x, c1.y, c1.z, c1.w};
                float b2[4] = {c2.x, c2.y, c2.z, c2.w};
                #pragma unroll
                for (int i = 0; i < 4; ++i)
                    #pragma unroll
                    for (int j = 0; j < 4; ++j) {
                        acc1[i][j] = fmaf(rr[i], b1[j], acc1[i][j]);
                        acc2[i][j] = fmaf(rr[i], b2[j], acc2[i][j]);
                    }
            }
        }
    } else {
        for (int kc = 0; kc < ND; kc += 16) {
            __syncthreads();
            T0[lk4 + 0][lrow] = v0.x; T0[lk4 + 1][lrow] = v0.y;
            T0[lk4 + 2][lrow] = v0.z; T0[lk4 + 3][lrow] = v0.w;
            T1[lk4 + 0][lrow] = v1.x; T1[lk4 + 1][lrow] = v1.y;
            T1[lk4 + 2][lrow] = v1.z; T1[lk4 + 3][lrow] = v1.w;
            T2[lk4 + 0][lrow] = v2.x; T2[lk4 + 1][lrow] = v2.y;
            T2[lk4 + 2][lrow] = v2.z; T2[lk4 + 3][lrow] = v2.w;
            if (kc + 16 < ND) {
                v0 = *(const float4*)(p0 + kc + 16);
                v1 = *(const float4*)(p1 + kc + 16);
                v2 = *(const float4*)(p2 + kc + 16);
            }
            __syncthreads();
            #pragma unroll
            for (int k = 0; k < 16; ++k) {
                float4 r1 = *(const float4*)&T1[k][ty4];   // txt anchors
                float4 r2 = *(const float4*)&T2[k][ty4];   // cr anchors
                float4 cv = *(const float4*)&T0[k][tx4];   // shared cols (img)
                float a1[4] = {r1.x, r1.y, r1.z, r1.w};
                float a2[4] = {r2.x, r2.y, r2.z, r2.w};
                float bb[4] = {cv.x, cv.y, cv.z, cv.w};
                #pragma unroll
                for (int i = 0; i < 4; ++i)
                    #pragma unroll
                    for (int j = 0; j < 4; ++j) {
                        acc1[i][j] = fmaf(a1[i], bb[j], acc1[i][j]);
                        acc2[i][j] = fmaf(a2[i], bb[j], acc2[i][j]);
                    }
            }
        }
    }
    __syncthreads();

    // predicate pass: first valid (min col) via atomicMin, both z's
    #pragma unroll
    for (int i = 0; i < 4; ++i) {
        int r = ty4 + i;
        int la = aLab[r];
        float mg1 = aMg1[r];
        if (!(flag && mg1 < 0.16f)) {
            float dg = aDg1[r], rn = aRn1[r];
            #pragma unroll
            for (int j = 0; j < 4; ++j) {
                int c = tx4 + j;
                if (cLab[c] == la) continue;
                float lm = acc1[i][j] * rn * cRn1[c] - dg + mg1;
                if (lm > 0.0f && lm < mg1) atomicMin(&res1[r], c);
            }
        }
        float mg2 = aMg2[r];
        if (!(flag && mg2 < 0.16f)) {
            float dg = aDg2[r], rn = aRn2[r];
            #pragma unroll
            for (int j = 0; j < 4; ++j) {
                int c = tx4 + j;
                if (cLab[c] == la) continue;
                float lm = acc2[i][j] * rn * cRn2[c] - dg + mg2;
                if (lm > 0.0f && lm < mg2) atomicMin(&res2[r], c);
            }
        }
    }
    __syncthreads();

    // winner pass: unique owner thread of the winning column adds lm
    #pragma unroll
    for (int i = 0; i < 4; ++i) {
        int r = ty4 + i;
        int w = res1[r];
        if (w >= 0 && w != INT_MAX) {
            int c = w - tx4;
            if (c >= 0 && c <= 3) {
                float lm = acc1[i][c] * aRn1[r] * cRn1[w] - aDg1[r] + aMg1[r];
                atomicAdd(&bAcc1, lm);
            }
        }
        int w2 = res2[r];
        if (w2 >= 0 && w2 != INT_MAX) {
            int c = w2 - tx4;
            if (c >= 0 && c <= 3) {
                float lm = acc2[i][c] * aRn2[r] * cRn2[w2] - aDg2[r] + aMg2[r];
                atomicAdd(&bAcc2, lm);
            }
        }
    }
    __syncthreads();

    if (tid < 64) {
        if (res1[tid] == INT_MAX) {            // z = pair
            int pos = atomicAdd(&stragCnt[pair], 1);
            stragList[pair * NB + pos] = a0 + tid;
        }
        if (res2[tid] == INT_MAX) {            // z = pair + 2
            int pos = atomicAdd(&stragCnt[pair + 2], 1);
            stragList[(pair + 2) * NB + pos] = a0 + tid;
        }
    }
    if (tid == 0) {
        float t = bAcc1 + betap[0] * bAcc2;    // second z is the CR pass
        if (t != 0.0f) atomicAdd(out, t);
    }
}

// 32x64xK=512 fp32 tile (wina). LDS padded so staging writes are 2-way (free).
template <bool GATHER>
__device__ __forceinline__ void gemm32x64(
        const float* __restrict__ A, const float* __restrict__ B,
        int a0, const int* aRow, int c0,
        float (&As)[16][36], float (&Bs)[16][68],
        float (&acc)[2][4], int tid) {
    const int lrow = tid >> 2, lk4 = (tid & 3) * 4;
    const bool doA = tid < 128;
    const int arow = GATHER ? (doA ? aRow[lrow] : 0) : (a0 + (lrow & 31));
    float4 va, vb;
    if (doA) va = *(const float4*)(A + (size_t)arow * ND + lk4);
    vb = *(const float4*)(B + (size_t)(c0 + lrow) * ND + lk4);
    for (int kc = 0; kc < ND; kc += 16) {
        __syncthreads();                       // prior compute done
        if (doA) {
            As[lk4 + 0][lrow] = va.x; As[lk4 + 1][lrow] = va.y;
            As[lk4 + 2][lrow] = va.z; As[lk4 + 3][lrow] = va.w;
        }
        Bs[lk4 + 0][lrow] = vb.x; Bs[lk4 + 1][lrow] = vb.y;
        Bs[lk4 + 2][lrow] = vb.z; Bs[lk4 + 3][lrow] = vb.w;
        if (kc + 16 < ND) {                    // software-pipelined prefetch
            if (doA) va = *(const float4*)(A + (size_t)arow * ND + kc + 16 + lk4);
            vb = *(const float4*)(B + (size_t)(c0 + lrow) * ND + kc + 16 + lk4);
        }
        __syncthreads();
        const int ty2 = (tid >> 4) * 2, tx4 = (tid & 15) * 4;
        #pragma unroll
        for (int k = 0; k < 16; ++k) {
            float2 av = *(const float2*)&As[k][ty2];
            float4 bv = *(const float4*)&Bs[k][tx4];
            #pragma unroll
            for (int i = 0; i < 2; ++i) {
                float ai = i ? av.y : av.x;
                acc[i][0] = fmaf(ai, bv.x, acc[i][0]);
                acc[i][1] = fmaf(ai, bv.y, acc[i][1]);
                acc[i][2] = fmaf(ai, bv.z, acc[i][2]);
                acc[i][3] = fmaf(ai, bv.w, acc[i][3]);
            }
        }
    }
}

// wina: gathered 32-straggler tiles x 64-col chunks over [64,1088).
__global__ __launch_bounds__(256) void wina_k(
        const float* __restrict__ img, const float* __restrict__ txt,
        const float* __restrict__ cr, const int* __restrict__ labels,
        const float* __restrict__ margin,
        const float* rnImg, const float* rnTxt, const float* rnCr,
        const float* dgSim, const float* dgCr, const float* mgCr,
        const int* stragCnt, const int* stragList, int* negIdx) {
    __shared__ __align__(16) float As[16][36];
    __shared__ __align__(16) float Bs[16][68];
    __shared__ float aRn[32], aDg[32], aMg[32], colRn[64];
    __shared__ int   aId[32], aRow[32], aLab[32], colLab[64];

    const int tid = threadIdx.x, z = blockIdx.y;
    const int chunk = blockIdx.x & (WCHUNKS - 1);
    const int t     = blockIdx.x / WCHUNKS;
    const int cnt = stragCnt[z];
    if (t * 32 >= cnt) return;                 // uniform: no anchors here
    const int c0 = 64 + chunk * 64;

    const float *A, *B, *rnA, *rnB, *dgA, *mgA;
    pass_arrays(z, img, txt, cr, rnImg, rnTxt, rnCr, dgSim, dgCr, margin, mgCr,
                A, B, rnA, rnB, dgA, mgA);

    if (tid < 32) {
        int s = t * 32 + tid;
        int a = (s < cnt) ? stragList[z * NB + s] : -1;
        int ar = (a >= 0) ? a : 0;             // dummy row for padding lanes
        aId[tid] = a; aRow[tid] = ar;
        aRn[tid] = rnA[ar]; aDg[tid] = dgA[ar]; aMg[tid] = mgA[ar];
        aLab[tid] = labels[ar];
    }
    if (tid < 64) { colRn[tid] = rnB[c0 + tid]; colLab[tid] = labels[c0 + tid]; }
    __syncthreads();

    float acc[2][4] = {};
    gemm32x64<true>(A, B, 0, aRow, c0, As, Bs, acc, tid);
    __syncthreads();

    const int ty2 = (tid >> 4) * 2, tx4 = (tid & 15) * 4;
    #pragma unroll
    for (int i = 0; i < 2; ++i) {
        int r = ty2 + i;
        int a = aId[r];
        if (a < 0) continue;
        float dg = aDg[r], mgv = aMg[r], rna = aRn[r];
        int la = aLab[r];
        #pragma unroll
        for (int j = 0; j < 4; ++j) {
            int c = tx4 + j;
            if (colLab[c] == la) continue;
            float lm = acc[i][j] * rna * colRn[c] - dg + mgv;
            if (lm > 0.0f && lm < mgv) atomicMin(&negIdx[z * NB + a], c0 + c);
        }
    }
}

__device__ inline float dot8(const float4& a0, const float4& a1,
                             const float4& b0, const float4& b1) {
    return a0.x*b0.x + a0.y*b0.y + a0.z*b0.z + a0.w*b0.w
         + a1.x*b1.x + a1.y*b1.y + a1.z*b1.z + a1.w*b1.w;
}

// tail: survivors of wina swept over 32-col chunks (254x4 blocks ~3.5/CU).
// Survivor loop bounded by gn; A-stage only gn rows; wina range skipped.
__global__ __launch_bounds__(256) void tail_k(
        const float* __restrict__ img, const float* __restrict__ txt,
        const float* __restrict__ cr, const int* __restrict__ labels,
        const float* __restrict__ margin,
        const float* rnImg, const float* rnTxt, const float* rnCr,
        const float* dgSim, const float* dgCr, const float* mgCr,
        const int* stragCnt, const int* stragList, int* negIdx) {
    __shared__ __align__(16) float Aload[8][ND];   // 16 KB
    __shared__ float sRn[8], sDg[8], sMg[8];
    __shared__ int   sLab[8], sAid[8];
    __shared__ float colRn_s[32];
    __shared__ int   colLab_s[32];
    __shared__ int   sSurv[256];
    __shared__ int   sNa;

    const int tid = threadIdx.x, z = blockIdx.y;
    const int c0 = 64 + blockIdx.x * 32;
    const int cnt = stragCnt[z];
    if (cnt == 0) return;
    // wina fully covered [64,1088) unless its 256-straggler capacity overflowed
    if (cnt <= WTILES * 32 && c0 < 64 + WCHUNKS * 64) return;

    const float *A, *B, *rnA, *rnB, *dgA, *mgA;
    pass_arrays(z, img, txt, cr, rnImg, rnTxt, rnCr, dgSim, dgCr, margin, mgCr,
                A, B, rnA, rnB, dgA, mgA);

    // survivor compaction (order irrelevant: result is a global min)
    if (tid == 0) sNa = 0;
    __syncthreads();
    for (int s = tid; s < cnt; s += 256) {
        int a = stragList[z * NB + s];
        if (negIdx[z * NB + a] == INT_MAX) {
            int p = atomicAdd(&sNa, 1);
            if (p < 256) sSurv[p] = a;
        }
    }
    __syncthreads();
    const int na = min(sNa, 256);
    if (na == 0) return;

    if (tid < 32) { colRn_s[tid] = rnB[c0 + tid]; colLab_s[tid] = labels[c0 + tid]; }

    const int wv = tid >> 6, lane = tid & 63;

    for (int g0 = 0; g0 < na; g0 += 8) {
        const int gn = min(8, na - g0);
        __syncthreads();                       // protect Aload/params reuse
        if (tid < 8) {
            int s = g0 + ((tid < gn) ? tid : 0);
            int a = sSurv[s];
            sAid[tid] = (tid < gn) ? a : -1;
            sRn[tid] = rnA[a]; sDg[tid] = dgA[a]; sMg[tid] = mgA[a];
            sLab[tid] = labels[a];
        }
        #pragma unroll
        for (int m = 0; m < 4; ++m) {          // stage gn survivor rows
            int idx = tid + m * 256;
            int row = idx >> 7, f4 = idx & 127;
            if (row < gn) {
                int a = sSurv[g0 + row];
                *(float4*)&Aload[row][f4 * 4] =
                    *(const float4*)(A + (size_t)a * ND + f4 * 4);
            }
        }
        __syncthreads();

        // each wave: 8 cols, in batches of 4 (B loads shared across survivors)
        #pragma unroll
        for (int cb = 0; cb < 2; ++cb) {
            const int cc0 = wv * 8 + cb * 4;
            float4 b0[4], b1[4];
            #pragma unroll
            for (int q = 0; q < 4; ++q) {
                const float4* Bv = (const float4*)(B + (size_t)(c0 + cc0 + q) * ND);
                b0[q] = Bv[lane]; b1[q] = Bv[lane + 64];
            }
            for (int s = 0; s < gn; ++s) {     // gn-bounded: no padding work
                float4 a0v = *(const float4*)&Aload[s][lane * 4];
                float4 a1v = *(const float4*)&Aload[s][(lane + 64) * 4];
                float d0 = dot8(a0v, a1v, b0[0], b1[0]);
                float d1 = dot8(a0v, a1v, b0[1], b1[1]);
                float d2 = dot8(a0v, a1v, b0[2], b1[2]);
                float d3 = dot8(a0v, a1v, b0[3], b1[3]);
                #pragma unroll
                for (int off = 1; off < 64; off <<= 1) {
                    d0 += __shfl_xor(d0, off); d1 += __shfl_xor(d1, off);
                    d2 += __shfl_xor(d2, off); d3 += __shfl_xor(d3, off);
                }
                if (lane == 0) {
                    int aid = sAid[s];
                    float rn = sRn[s], dg = sDg[s], mg = sMg[s];
                    int lb = sLab[s];
                    float dv[4] = {d0, d1, d2, d3};
                    #pragma unroll
                    for (int q = 0; q < 4; ++q) {
                        int cc = cc0 + q;
                        if (colLab_s[cc] != lb) {
                            float lm = dv[q] * rn * colRn_s[cc] - dg + mg;
                            if (lm > 0.0f && lm < mg)
                                atomicMin(&negIdx[z * NB + aid], c0 + cc);
                        }
                    }
                }
            }
        }
    }
}

// Recompute winning sim value per straggler, block-reduce, accumulate.
__global__ __launch_bounds__(256) void final_k(
        const float* __restrict__ img, const float* __restrict__ txt,
        const float* __restrict__ cr,
        const float* rnImg, const float* rnTxt, const float* rnCr,
        const float* dgSim, const float* dgCr,
        const float* __restrict__ margin, const float* mgCr,
        const float* __restrict__ betap,
        const int* stragCnt, const int* stragList, const int* negIdx,
        float* out) {
    __shared__ float s4[4];
    const int tid = threadIdx.x, z = blockIdx.y;
    const float *A, *B, *rnA, *rnB, *dgA, *mgA;
    pass_arrays(z, img, txt, cr, rnImg, rnTxt, rnCr, dgSim, dgCr, margin, mgCr,
                A, B, rnA, rnB, dgA, mgA);
    int t = blockIdx.x * 256 + tid;
    float contrib = 0.0f;
    if (t < stragCnt[z]) {
        int a = stragList[z * NB + t];
        int idx = negIdx[z * NB + a];
        if (idx != INT_MAX) {
            const float4* Av = (const float4*)(A + (size_t)a   * ND);
            const float4* Bv = (const float4*)(B + (size_t)idx * ND);
            float d = 0.0f;
            #pragma unroll 8
            for (int i = 0; i < ND / 4; ++i) {
                float4 x = Av[i], y = Bv[i];
                d += x.x*y.x + x.y*y.y + x.z*y.z + x.w*y.w;
            }
            float lm = d * rnA[a] * rnB[idx] - dgA[a] + mgA[a];
            contrib = fmaxf(lm, 0.0f);
        }
    }
    #pragma unroll
    for (int off = 32; off; off >>= 1) contrib += __shfl_xor(contrib, off);
    if ((tid & 63) == 0) s4[tid >> 6] = contrib;
    __syncthreads();
    if (tid == 0) {
        float sum = s4[0] + s4[1] + s4[2] + s4[3];
        if (sum != 0.0f) atomicAdd(out, sum * ((z >= 2) ? betap[0] : 1.0f));
    }
}

// ===========================================================================
// Fallback path (no workspace) — the proven round-3 single-kernel version.
// ===========================================================================

__global__ __launch_bounds__(256) void zero_k(float* out, int n) {
    int g = blockIdx.x * 256 + threadIdx.x;
    if (g < n) out[g] = 0.0f;
}

template <int U>
__device__ void stragScan(const float* __restrict__ A, const float* __restrict__ B,
                          const int* __restrict__ labels, int a0, int u, int scol,
                          const int* sList, int g0,
                          const float* aRn, const float* aDg, const float* aMg,
                          const int* aLab, int* sMin8, int* doneMask,
                          float* blockAcc) {
    const int tid = threadIdx.x;
    float rn_s[U], dg_s[U], mg_s[U];
    int lab_s[U];
    const float4* Av[U];
    #pragma unroll
    for (int s = 0; s < U; ++s) {
        int slot = sList[g0 + (s < u ? s : 0)];
        rn_s[s] = aRn[slot]; dg_s[s] = aDg[slot]; mg_s[s] = aMg[slot];
        lab_s[s] = aLab[slot];
        Av[s] = (const float4*)(A + (size_t)(a0 + slot) * ND);
    }
    if (tid < U) sMin8[tid] = INT_MAX;
    if (tid == 0) *doneMask = 0;
    __syncthreads();
    for (int jb = scol; jb < NB; jb += 256) {
        int j = jb + tid;
        bool jv = (j < NB);
        int mask = *doneMask;
        float dot[U];
        #pragma unroll
        for (int s = 0; s < U; ++s) dot[s] = 0.0f;
        float ssq = 0.0f;
        if (jv) {
            const float4* Bv = (const float4*)(B + (size_t)j * ND);
            #pragma unroll 4
            for (int k4 = 0; k4 < ND / 4; ++k4) {
                float4 b = Bv[k4];
                ssq += b.x*b.x + b.y*b.y + b.z*b.z + b.w*b.w;
                #pragma unroll
                for (int s = 0; s < U; ++s) {
                    float4 a = Av[s][k4];
                    dot[s] += a.x*b.x + a.y*b.y + a.z*b.z + a.w*b.w;
                }
            }
        }
        float rnb = 1.0f / (sqrtf(ssq) + 1e-8f);
        int lj = jv ? labels[j] : -1;
        float lmv[U];
        #pragma unroll
        for (int s = 0; s < U; ++s) {
            lmv[s] = dot[s] * rn_s[s] * rnb - dg_s[s] + mg_s[s];
            if (jv && s < u && !((mask >> s) & 1) && lj != lab_s[s] &&
                lmv[s] > 0.0f && lmv[s] < mg_s[s])
                atomicMin(&sMin8[s], j);
        }
        __syncthreads();
        #pragma unroll
        for (int s = 0; s < U; ++s)
            if (jv && s < u && !((mask >> s) & 1) && sMin8[s] == j)
                atomicAdd(blockAcc, lmv[s]);
        __syncthreads();
        if (tid == 0) {
            int m2 = 0;
            for (int s = 0; s < u; ++s)
                if (sMin8[s] != INT_MAX) m2 |= (1 << s);
            *doneMask = m2;
        }
        __syncthreads();
        if (*doneMask == (1 << u) - 1) break;
    }
}

__global__ __launch_bounds__(256) void mine_k(const float* __restrict__ img,
                                              const float* __restrict__ txt,
                                              const float* __restrict__ cr,
                                              const int*   __restrict__ labels,
                                              const int*   __restrict__ flagp,
                                              const float* __restrict__ margin,
                                              const float* __restrict__ betap,
                                              float* __restrict__ out) {
    __shared__ __align__(16) float As[16][64];
    __shared__ __align__(16) float Bs[16][64];
    __shared__ float aRn[64], aDg[64], aMg[64];
    __shared__ int   aLab[64];
    __shared__ float colRn[64];
    __shared__ int   colLab[64];
    __shared__ int   resIdx[64], prevIdx[64];
    __shared__ int   cnt;
    __shared__ float blockAcc;
    __shared__ int   sList[64];
    __shared__ int   sCnt;
    __shared__ int   sMin8[8];
    __shared__ int   doneMask;

    const int tid  = threadIdx.x;
    const int z    = blockIdx.y;
    const int a0   = blockIdx.x * 64;
    const int flag = flagp[0];
    const float* A = (z == 1) ? txt : (z == 3) ? cr : img;
    const float* B = (z == 0) ? txt : (z == 2) ? cr : img;
    {
        int ar = tid >> 2, q = tid & 3;
        int a  = a0 + ar;
        const float4* iv = (const float4*)(img + (size_t)a * ND) + q * 32;
        const float4* tv = (const float4*)(txt + (size_t)a * ND) + q * 32;
        const float4* cv = (const float4*)(cr  + (size_t)a * ND) + q * 32;
        float sii = 0, stt = 0, scc = 0, sit = 0, sic = 0;
        #pragma unroll 4
        for (int i = 0; i < 32; ++i) {
            float4 x = iv[i], y = tv[i], w = cv[i];
            sii += x.x*x.x + x.y*x.y + x.z*x.z + x.w*x.w;
            stt += y.x*y.x + y.y*y.y + y.z*y.z + y.w*y.w;
            scc += w.x*w.x + w.y*w.y + w.z*w.z + w.w*w.w;
            sit += x.x*y.x + x.y*y.y + x.z*y.z + x.w*y.w;
            sic += x.x*w.x + x.y*w.y + x.z*w.z + x.w*w.w;
        }
        sii += __shfl_xor(sii, 1); sii += __shfl_xor(sii, 2);
        stt += __shfl_xor(stt, 1); stt += __shfl_xor(stt, 2);
        sit += __shfl_xor(sit, 1); sit += __shfl_xor(sit, 2);
        scc += __shfl_xor(scc, 1); scc += __shfl_xor(scc, 2);
        sic += __shfl_xor(sic, 1); sic += __shfl_xor(sic, 2);
        if (q == 0) {
            float rnI = 1.0f / (sqrtf(sii) + 1e-8f);
            float rnT = 1.0f / (sqrtf(stt) + 1e-8f);
            float ds  = sit * rnI * rnT;
            float m   = margin[a];
            float mg, rna, dgv;
            if (z >= 2) {
                float rnC = 1.0f / (sqrtf(scc) + 1e-8f);
                float dc  = sic * rnI * rnC;
                mg = flag ? (fminf(fabsf(dc) / fabsf(ds), 1.0f) + 1.0f) * m * 0.5f
                          : m * 0.5f;
                dgv = dc; rna = (z == 3) ? rnC : rnI;
            } else {
                mg = m; dgv = ds; rna = (z == 1) ? rnT : rnI;
            }
            aRn[ar] = rna; aDg[ar] = dgv; aMg[ar] = mg; aLab[ar] = labels[a];
            resIdx[ar] = (flag && mg < 0.16f) ? -1 : INT_MAX;
        }
        if (tid == 0) blockAcc = 0.0f;
    }
    __syncthreads();
    const int ty4  = (tid >> 4) * 4, tx4 = (tid & 15) * 4;
    const int lrow = tid >> 2,  lk4 = (tid & 3) * 4;
    int bandCols = 0, unresolved = 64;
    for (int jc = 0; jc < 2; ++jc) {
        int j0 = jc * 64;
        float acc[4][4];
        #pragma unroll
        for (int i = 0; i < 4; ++i)
            #pragma unroll
            for (int j = 0; j < 4; ++j) acc[i][j] = 0.0f;
        float bssq = 0.0f;
        for (int kc = 0; kc < ND; kc += 16) {
            __syncthreads();
            float4 va = *(const float4*)(A + (size_t)(a0 + lrow) * ND + kc + lk4);
            float4 vb = *(const float4*)(B + (size_t)(j0 + lrow) * ND + kc + lk4);
            As[lk4 + 0][lrow] = va.x; As[lk4 + 1][lrow] = va.y;
            As[lk4 + 2][lrow] = va.z; As[lk4 + 3][lrow] = va.w;
            Bs[lk4 + 0][lrow] = vb.x; Bs[lk4 + 1][lrow] = vb.y;
            Bs[lk4 + 2][lrow] = vb.z; Bs[lk4 + 3][lrow] = vb.w;
            bssq += vb.x*vb.x + vb.y*vb.y + vb.z*vb.z + vb.w*vb.w;
            __syncthreads();
            #pragma unroll
            for (int k = 0; k < 16; ++k) {
                float4 av = *(const float4*)&As[k][ty4];
                float4 bv = *(const float4*)&Bs[k][tx4];
                float ar[4] = {av.x, av.y, av.z, av.w};
                float br[4] = {bv.x, bv.y, bv.z, bv.w};
                #pragma unroll
                for (int i = 0; i < 4; ++i)
                    #pragma unroll
                    for (int j = 0; j < 4; ++j)
                        acc[i][j] = fmaf(ar[i], br[j], acc[i][j]);
            }
        }
        bssq += __shfl_xor(bssq, 1); bssq += __shfl_xor(bssq, 2);
        __syncthreads();
        if ((tid & 3) == 0) {
            colRn[lrow]  = 1.0f / (sqrtf(bssq) + 1e-8f);
            colLab[lrow] = labels[j0 + lrow];
        }
        if (tid < 64) prevIdx[tid] = resIdx[tid];
        __syncthreads();
        #pragma unroll
        for (int i = 0; i < 4; ++i) {
            int r = ty4 + i;
            if (prevIdx[r] != INT_MAX) continue;
            float dg = aDg[r], mgv = aMg[r], rna = aRn[r];
            int la = aLab[r];
            #pragma unroll
            for (int j = 0; j < 4; ++j) {
                int c = tx4 + j;
                if (colLab[c] == la) continue;
                float v  = acc[i][j] * rna * colRn[c];
                float lm = v - dg + mgv;
                if (lm > 0.0f && lm < mgv) atomicMin(&resIdx[r], j0 + c);
            }
        }
        __syncthreads();
        #pragma unroll
        for (int i = 0; i < 4; ++i) {
            int r = ty4 + i;
            if (prevIdx[r] != INT_MAX) continue;
            int w = resIdx[r];
            if (w == INT_MAX) continue;
            int c = w - j0 - tx4;
            if (c < 0 || c > 3) continue;
            float v  = acc[i][c] * aRn[r] * colRn[tx4 + c];
            float lm = v - aDg[r] + aMg[r];
            atomicAdd(&blockAcc, lm);
        }
        __syncthreads();
        if (tid == 0) cnt = 0;
        __syncthreads();
        if (tid < 64 && resIdx[tid] == INT_MAX) atomicAdd(&cnt, 1);
        __syncthreads();
        unresolved = cnt;
        bandCols = j0 + 64;
        __syncthreads();
        if (unresolved <= 8) break;
    }
    if (unresolved > 0) {
        if (tid == 0) sCnt = 0;
        __syncthreads();
        if (tid < 64 && resIdx[tid] == INT_MAX) {
            int pos = atomicAdd(&sCnt, 1);
            sList[pos] = tid;
        }
        __syncthreads();
        int total = sCnt;
        for (int g0 = 0; g0 < total; g0 += 8) {
            int u = min(8, total - g0);
            if (u == 1)      stragScan<1>(A, B, labels, a0, u, bandCols, sList, g0, aRn, aDg, aMg, aLab, sMin8, &doneMask, &blockAcc);
            else if (u == 2) stragScan<2>(A, B, labels, a0, u, bandCols, sList, g0, aRn, aDg, aMg, aLab, sMin8, &doneMask, &blockAcc);
            else if (u <= 4) stragScan<4>(A, B, labels, a0, u, bandCols, sList, g0, aRn, aDg, aMg, aLab, sMin8, &doneMask, &blockAcc);
            else             stragScan<8>(A, B, labels, a0, u, bandCols, sList, g0, aRn, aDg, aMg, aLab, sMin8, &doneMask, &blockAcc);
            __syncthreads();
        }
    }
    if (tid == 0 && blockAcc != 0.0f) {
        float scale = (z >= 2) ? betap[0] : 1.0f;
        atomicAdd(out, blockAcc * scale);
    }
}

// ===========================================================================

extern "C" void kernel_launch(void* const* d_in, const int* in_sizes, int n_in,
                              void* d_out, int out_size, void* d_ws, size_t ws_size,
                              hipStream_t stream) {
    const float* img    = (const float*)d_in[0];
    const float* txt    = (const float*)d_in[1];
    const float* cr     = (const float*)d_in[2];
    const int*   labels = (const int*)  d_in[3];
    const int*   flagp  = (const int*)  d_in[4];
    const float* marg   = (const float*)d_in[5];
    const float* betap  = (const float*)d_in[6];
    float* out = (float*)d_out;
    (void)in_sizes; (void)n_in;

    const size_t REQ = (size_t)(6 * NB) * 4 + (size_t)(4 * NB) * 4 + 64 +
                       (size_t)(4 * NB) * 4;
    if (ws_size >= REQ) {
        float* wf = (float*)d_ws;
        float* rnImg = wf + 0 * NB;
        float* rnTxt = wf + 1 * NB;
        float* rnCr  = wf + 2 * NB;
        float* dgSim = wf + 3 * NB;
        float* dgCr  = wf + 4 * NB;
        float* mgCr  = wf + 5 * NB;
        int* negIdx    = (int*)(wf + 6 * NB);
        int* stragCnt  = negIdx + 4 * NB;
        int* stragList = stragCnt + 16;

        stats_k<<<dim3(NB / 16),              dim3(256), 0, stream>>>(
            img, txt, cr, marg, flagp,
            rnImg, rnTxt, rnCr, dgSim, dgCr, mgCr, negIdx, stragCnt, out);
        band2_k<<<dim3(NB / 64, 2),           dim3(256), 0, stream>>>(
            img, txt, cr, labels, flagp, marg, betap,
            rnImg, rnTxt, rnCr, dgSim, dgCr, mgCr, stragCnt, stragList, out);
        wina_k <<<dim3(WCHUNKS * WTILES, 4),  dim3(256), 0, stream>>>(
            img, txt, cr, labels, marg,
            rnImg, rnTxt, rnCr, dgSim, dgCr, mgCr,
            stragCnt, stragList, negIdx);
        tail_k <<<dim3(TCHUNKS, 4),           dim3(256), 0, stream>>>(
            img, txt, cr, labels, marg,
            rnImg, rnTxt, rnCr, dgSim, dgCr, mgCr,
            stragCnt, stragList, negIdx);
        final_k<<<dim3(NB / 256, 4),          dim3(256), 0, stream>>>(
            img, txt, cr, rnImg, rnTxt, rnCr, dgSim, dgCr, marg, mgCr, betap,
            stragCnt, stragList, negIdx, out);
    } else {
        zero_k<<<dim3((out_size + 255) / 256), dim3(256), 0, stream>>>(out, out_size);
        mine_k<<<dim3(NB / 64, 4), dim3(256), 0, stream>>>(img, txt, cr, labels,
                                                           flagp, marg, betap, out);
    }
}

// Round 5
// 219.472 us; speedup vs baseline: 1.1031x; 1.0346x over previous
//
#include <hip/hip_runtime.h>
#include <climits>

// Problem constants (fixed by the reference): B=8192 rows, D=512 features.
#define NB 8192
#define ND 512

// Straggler resolution:
//   wina_k: cols [64, 64+WCHUNKS*32) = [64,1088), up to WTILES*64 stragglers/z
//   tail_k: cols [64, NB) for the survivors (expected ~2/z after wina),
//           32-col chunks; skips [64,1088) unless wina capacity overflowed.
#define WCHUNKS 32
#define WTILES 4
#define WCAP (WTILES * 64)          // 256 stragglers/z
#define WCOLS (64 + WCHUNKS * 32)   // 1088
#define TCHUNKS ((NB - 64) / 32)    // 254

// ===========================================================================
// Fast path: stats -> band -> wina -> tail -> final through d_ws.
// ws layout (floats): rnImg rnTxt rnCr dgSim dgCr mgCr [6*NB]
//            (ints):  negIdx [4*NB], stragCnt [16], stragList [4*NB]
// ===========================================================================

// Per-row stats + workspace init. 16 threads/row, 16 rows/block, 512 blocks.
__global__ __launch_bounds__(256) void stats_k(
        const float* __restrict__ img, const float* __restrict__ txt,
        const float* __restrict__ cr, const float* __restrict__ margin,
        const int* __restrict__ flagp,
        float* rnImg, float* rnTxt, float* rnCr,
        float* dgSim, float* dgCr, float* mgCr,
        int* negIdx, int* stragCnt, float* out) {
    int tid = threadIdx.x, bid = blockIdx.x;
    int g = bid * 256 + tid;
    if (g < 4 * NB) negIdx[g] = INT_MAX;
    if (bid == 0 && tid < 8) stragCnt[tid] = 0;
    if (bid == 0 && tid == 0) out[0] = 0.0f;

    int r = bid * 16 + (tid >> 4);
    int q = tid & 15;
    const float4* iv = (const float4*)(img + (size_t)r * ND);
    const float4* tv = (const float4*)(txt + (size_t)r * ND);
    const float4* cv = (const float4*)(cr  + (size_t)r * ND);
    float sii = 0, stt = 0, scc = 0, sit = 0, sic = 0;
    #pragma unroll
    for (int i = 0; i < 8; ++i) {                 // lane-contiguous: coalesced
        int k = q + i * 16;
        float4 x = iv[k], y = tv[k], w = cv[k];
        sii += x.x*x.x + x.y*x.y + x.z*x.z + x.w*x.w;
        stt += y.x*y.x + y.y*y.y + y.z*y.z + y.w*y.w;
        scc += w.x*w.x + w.y*w.y + w.z*w.z + w.w*w.w;
        sit += x.x*y.x + x.y*y.y + x.z*y.z + x.w*y.w;
        sic += x.x*w.x + x.y*w.y + x.z*w.z + x.w*w.w;
    }
    #pragma unroll
    for (int off = 1; off < 16; off <<= 1) {
        sii += __shfl_xor(sii, off); stt += __shfl_xor(stt, off);
        scc += __shfl_xor(scc, off); sit += __shfl_xor(sit, off);
        sic += __shfl_xor(sic, off);
    }
    if (q == 0) {
        float rnI = 1.0f / (sqrtf(sii) + 1e-8f);
        float rnT = 1.0f / (sqrtf(stt) + 1e-8f);
        float rnC = 1.0f / (sqrtf(scc) + 1e-8f);
        float ds = sit * rnI * rnT;
        float dc = sic * rnI * rnC;
        float m  = margin[r];
        float mcr = flagp[0] ? (fminf(fabsf(dc) / fabsf(ds), 1.0f) + 1.0f) * m * 0.5f
                             : m * 0.5f;
        rnImg[r] = rnI; rnTxt[r] = rnT; rnCr[r] = rnC;
        dgSim[r] = ds;  dgCr[r]  = dc;  mgCr[r] = mcr;
    }
}

__device__ inline void pass_arrays(int z,
        const float* img, const float* txt, const float* cr,
        const float* rnImg, const float* rnTxt, const float* rnCr,
        const float* dgSim, const float* dgCr,
        const float* margin, const float* mgCr,
        const float*& A, const float*& B, const float*& rnA, const float*& rnB,
        const float*& dgA, const float*& mgA) {
    if (z == 0)      { A = img; B = txt; rnA = rnImg; rnB = rnTxt; dgA = dgSim; mgA = margin; }
    else if (z == 1) { A = txt; B = img; rnA = rnTxt; rnB = rnImg; dgA = dgSim; mgA = margin; }
    else if (z == 2) { A = img; B = cr;  rnA = rnImg; rnB = rnCr;  dgA = dgCr;  mgA = mgCr;   }
    else             { A = cr;  B = img; rnA = rnCr;  rnB = rnImg; dgA = dgCr;  mgA = mgCr;   }
}

// ---------------------------------------------------------------------------
// band: 64 anchors x 64 cols x K=512, acc[4][4] (R1 shape + R3 padding).
// Per kc-step a thread issues 2x b128 LDS reads per k for 16 FMA — half the
// LDS-pipe demand of the 32x64 acc[2][4] tile at the same per-CU work.
// Grid (NB/64, 4) = 512 blocks -> 2 blocks/CU. Stores 2-way aliased (free);
// A-read is a 16-lane broadcast; B-read 2-way (free).
// ---------------------------------------------------------------------------
__global__ __launch_bounds__(256) void band_k(
        const float* __restrict__ img, const float* __restrict__ txt,
        const float* __restrict__ cr, const int* __restrict__ labels,
        const int* __restrict__ flagp, const float* __restrict__ margin,
        const float* __restrict__ betap,
        const float* rnImg, const float* rnTxt, const float* rnCr,
        const float* dgSim, const float* dgCr, const float* mgCr,
        int* stragCnt, int* stragList, float* out) {
    __shared__ __align__(16) float As[16][68];
    __shared__ __align__(16) float Bs[16][68];
    __shared__ float aRn[64], aDg[64], aMg[64], colRn[64];
    __shared__ int   aLab[64], colLab[64], resIdx[64];
    __shared__ float blockAcc;

    const int tid = threadIdx.x, z = blockIdx.y, a0 = blockIdx.x * 64;
    const int flag = flagp[0];
    const float *A, *B, *rnA, *rnB, *dgA, *mgA;
    pass_arrays(z, img, txt, cr, rnImg, rnTxt, rnCr, dgSim, dgCr, margin, mgCr,
                A, B, rnA, rnB, dgA, mgA);

    if (tid < 64) {
        int a = a0 + tid;
        float mg = mgA[a];
        aRn[tid] = rnA[a]; aDg[tid] = dgA[a]; aMg[tid] = mg;
        aLab[tid] = labels[a];
        colRn[tid] = rnB[tid]; colLab[tid] = labels[tid];
        resIdx[tid] = (flag && mg < 0.16f) ? -1 : INT_MAX;
    }
    if (tid == 0) blockAcc = 0.0f;

    const int ty4  = (tid >> 4) * 4, tx4 = (tid & 15) * 4;
    const int lrow = tid >> 2,  lk4 = (tid & 3) * 4;

    float acc[4][4];
    #pragma unroll
    for (int i = 0; i < 4; ++i)
        #pragma unroll
        for (int j = 0; j < 4; ++j) acc[i][j] = 0.0f;

    // software-pipelined staging: prefetch next kc while computing current
    float4 va = *(const float4*)(A + (size_t)(a0 + lrow) * ND + lk4);
    float4 vb = *(const float4*)(B + (size_t)lrow * ND + lk4);
    for (int kc = 0; kc < ND; kc += 16) {
        __syncthreads();                       // prior compute done
        As[lk4 + 0][lrow] = va.x; As[lk4 + 1][lrow] = va.y;
        As[lk4 + 2][lrow] = va.z; As[lk4 + 3][lrow] = va.w;
        Bs[lk4 + 0][lrow] = vb.x; Bs[lk4 + 1][lrow] = vb.y;
        Bs[lk4 + 2][lrow] = vb.z; Bs[lk4 + 3][lrow] = vb.w;
        if (kc + 16 < ND) {
            va = *(const float4*)(A + (size_t)(a0 + lrow) * ND + kc + 16 + lk4);
            vb = *(const float4*)(B + (size_t)lrow * ND + kc + 16 + lk4);
        }
        __syncthreads();
        #pragma unroll
        for (int k = 0; k < 16; ++k) {
            float4 av = *(const float4*)&As[k][ty4];
            float4 bv = *(const float4*)&Bs[k][tx4];
            float ar[4] = {av.x, av.y, av.z, av.w};
            float br[4] = {bv.x, bv.y, bv.z, bv.w};
            #pragma unroll
            for (int i = 0; i < 4; ++i)
                #pragma unroll
                for (int j = 0; j < 4; ++j)
                    acc[i][j] = fmaf(ar[i], br[j], acc[i][j]);
        }
    }
    __syncthreads();

    // predicate pass: first valid (min col) via atomicMin
    #pragma unroll
    for (int i = 0; i < 4; ++i) {
        int r = ty4 + i;
        float mgv = aMg[r];
        if (flag && mgv < 0.16f) continue;     // pre-resolved: contributes 0
        float dg = aDg[r], rna = aRn[r];
        int la = aLab[r];
        #pragma unroll
        for (int j = 0; j < 4; ++j) {
            int c = tx4 + j;
            if (colLab[c] == la) continue;
            float lm = acc[i][j] * rna * colRn[c] - dg + mgv;
            if (lm > 0.0f && lm < mgv) atomicMin(&resIdx[r], c);
        }
    }
    __syncthreads();

    // winner pass: unique owner thread of the winning column adds lm
    #pragma unroll
    for (int i = 0; i < 4; ++i) {
        int r = ty4 + i;
        int w = resIdx[r];
        if (w < 0 || w == INT_MAX) continue;
        int c = w - tx4;
        if (c < 0 || c > 3) continue;
        float lm = acc[i][c] * aRn[r] * colRn[w] - aDg[r] + aMg[r];
        atomicAdd(&blockAcc, lm);
    }
    __syncthreads();

    if (tid < 64 && resIdx[tid] == INT_MAX) {  // unresolved -> global straggler
        int pos = atomicAdd(&stragCnt[z], 1);
        stragList[z * NB + pos] = a0 + tid;
    }
    if (tid == 0 && blockAcc != 0.0f) {
        float scale = (z >= 2) ? betap[0] : 1.0f;
        atomicAdd(out, blockAcc * scale);
    }
}

// ---------------------------------------------------------------------------
// wina: gathered 64-straggler tiles x 32-col chunks over [64,1088).
// Grid (WCHUNKS*WTILES, 4) = 512 blocks; inactive tiles exit immediately.
// acc[4][2]; A-read b128 broadcast, B-read b64; padded stores (free).
// ---------------------------------------------------------------------------
__global__ __launch_bounds__(256) void wina_k(
        const float* __restrict__ img, const float* __restrict__ txt,
        const float* __restrict__ cr, const int* __restrict__ labels,
        const float* __restrict__ margin,
        const float* rnImg, const float* rnTxt, const float* rnCr,
        const float* dgSim, const float* dgCr, const float* mgCr,
        const int* stragCnt, const int* stragList, int* negIdx) {
    __shared__ __align__(16) float As[16][68];
    __shared__ __align__(16) float Bs[16][36];
    __shared__ float aRn[64], aDg[64], aMg[64], colRn[32];
    __shared__ int   aId[64], aRow[64], aLab[64], colLab[32];

    const int tid = threadIdx.x, z = blockIdx.y;
    const int chunk = blockIdx.x & (WCHUNKS - 1);
    const int t     = blockIdx.x / WCHUNKS;
    const int cnt = stragCnt[z];
    if (t * 64 >= cnt) return;                 // uniform: no anchors here
    const int c0 = 64 + chunk * 32;

    const float *A, *B, *rnA, *rnB, *dgA, *mgA;
    pass_arrays(z, img, txt, cr, rnImg, rnTxt, rnCr, dgSim, dgCr, margin, mgCr,
                A, B, rnA, rnB, dgA, mgA);

    if (tid < 64) {
        int s = t * 64 + tid;
        int a = (s < cnt) ? stragList[z * NB + s] : -1;
        int ar = (a >= 0) ? a : 0;             // dummy row for padding lanes
        aId[tid] = a; aRow[tid] = ar;
        aRn[tid] = rnA[ar]; aDg[tid] = dgA[ar]; aMg[tid] = mgA[ar];
        aLab[tid] = labels[ar];
    }
    if (tid < 32) { colRn[tid] = rnB[c0 + tid]; colLab[tid] = labels[c0 + tid]; }
    __syncthreads();

    const int ty4  = (tid >> 4) * 4, tx2 = (tid & 15) * 2;
    const int lrow = tid >> 2,  lk4 = (tid & 3) * 4;
    const int arow = aRow[lrow];
    const bool doB = tid < 128;                // 32 B-rows x 4 f4-chunks

    float acc[4][2];
    #pragma unroll
    for (int i = 0; i < 4; ++i) { acc[i][0] = 0.0f; acc[i][1] = 0.0f; }

    float4 va = *(const float4*)(A + (size_t)arow * ND + lk4);
    float4 vb;
    if (doB) vb = *(const float4*)(B + (size_t)(c0 + lrow) * ND + lk4);
    for (int kc = 0; kc < ND; kc += 16) {
        __syncthreads();                       // prior compute done
        As[lk4 + 0][lrow] = va.x; As[lk4 + 1][lrow] = va.y;
        As[lk4 + 2][lrow] = va.z; As[lk4 + 3][lrow] = va.w;
        if (doB) {
            Bs[lk4 + 0][lrow] = vb.x; Bs[lk4 + 1][lrow] = vb.y;
            Bs[lk4 + 2][lrow] = vb.z; Bs[lk4 + 3][lrow] = vb.w;
        }
        if (kc + 16 < ND) {
            va = *(const float4*)(A + (size_t)arow * ND + kc + 16 + lk4);
            if (doB) vb = *(const float4*)(B + (size_t)(c0 + lrow) * ND + kc + 16 + lk4);
        }
        __syncthreads();
        #pragma unroll
        for (int k = 0; k < 16; ++k) {
            float4 av = *(const float4*)&As[k][ty4];
            float2 bv = *(const float2*)&Bs[k][tx2];
            float ar[4] = {av.x, av.y, av.z, av.w};
            #pragma unroll
            for (int i = 0; i < 4; ++i) {
                acc[i][0] = fmaf(ar[i], bv.x, acc[i][0]);
                acc[i][1] = fmaf(ar[i], bv.y, acc[i][1]);
            }
        }
    }
    __syncthreads();

    #pragma unroll
    for (int i = 0; i < 4; ++i) {
        int r = ty4 + i;
        int a = aId[r];
        if (a < 0) continue;
        float dg = aDg[r], mgv = aMg[r], rna = aRn[r];
        int la = aLab[r];
        #pragma unroll
        for (int j = 0; j < 2; ++j) {
            int c = tx2 + j;
            if (colLab[c] == la) continue;
            float lm = acc[i][j] * rna * colRn[c] - dg + mgv;
            if (lm > 0.0f && lm < mgv) atomicMin(&negIdx[z * NB + a], c0 + c);
        }
    }
}

__device__ inline float dot8(const float4& a0, const float4& a1,
                             const float4& b0, const float4& b1) {
    return a0.x*b0.x + a0.y*b0.y + a0.z*b0.z + a0.w*b0.w
         + a1.x*b1.x + a1.y*b1.y + a1.z*b1.z + a1.w*b1.w;
}

// tail: survivors of wina swept over 32-col chunks (254x4 blocks ~3.5/CU).
// Survivor loop bounded by gn; A-stage only gn rows; wina range skipped.
__global__ __launch_bounds__(256) void tail_k(
        const float* __restrict__ img, const float* __restrict__ txt,
        const float* __restrict__ cr, const int* __restrict__ labels,
        const float* __restrict__ margin,
        const float* rnImg, const float* rnTxt, const float* rnCr,
        const float* dgSim, const float* dgCr, const float* mgCr,
        const int* stragCnt, const int* stragList, int* negIdx) {
    __shared__ __align__(16) float Aload[8][ND];   // 16 KB
    __shared__ float sRn[8], sDg[8], sMg[8];
    __shared__ int   sLab[8], sAid[8];
    __shared__ float colRn_s[32];
    __shared__ int   colLab_s[32];
    __shared__ int   sSurv[256];
    __shared__ int   sNa;

    const int tid = threadIdx.x, z = blockIdx.y;
    const int c0 = 64 + blockIdx.x * 32;
    const int cnt = stragCnt[z];
    if (cnt == 0) return;
    // wina fully covered [64,1088) unless its capacity overflowed
    if (cnt <= WCAP && c0 < WCOLS) return;

    const float *A, *B, *rnA, *rnB, *dgA, *mgA;
    pass_arrays(z, img, txt, cr, rnImg, rnTxt, rnCr, dgSim, dgCr, margin, mgCr,
                A, B, rnA, rnB, dgA, mgA);

    // survivor compaction (order irrelevant: result is a global min)
    if (tid == 0) sNa = 0;
    __syncthreads();
    for (int s = tid; s < cnt; s += 256) {
        int a = stragList[z * NB + s];
        if (negIdx[z * NB + a] == INT_MAX) {
            int p = atomicAdd(&sNa, 1);
            if (p < 256) sSurv[p] = a;
        }
    }
    __syncthreads();
    const int na = min(sNa, 256);
    if (na == 0) return;

    if (tid < 32) { colRn_s[tid] = rnB[c0 + tid]; colLab_s[tid] = labels[c0 + tid]; }

    const int wv = tid >> 6, lane = tid & 63;

    for (int g0 = 0; g0 < na; g0 += 8) {
        const int gn = min(8, na - g0);
        __syncthreads();                       // protect Aload/params reuse
        if (tid < 8) {
            int s = g0 + ((tid < gn) ? tid : 0);
            int a = sSurv[s];
            sAid[tid] = (tid < gn) ? a : -1;
            sRn[tid] = rnA[a]; sDg[tid] = dgA[a]; sMg[tid] = mgA[a];
            sLab[tid] = labels[a];
        }
        #pragma unroll
        for (int m = 0; m < 4; ++m) {          // stage gn survivor rows
            int idx = tid + m * 256;
            int row = idx >> 7, f4 = idx & 127;
            if (row < gn) {
                int a = sSurv[g0 + row];
                *(float4*)&Aload[row][f4 * 4] =
                    *(const float4*)(A + (size_t)a * ND + f4 * 4);
            }
        }
        __syncthreads();

        // each wave: 8 cols, in batches of 4 (B loads shared across survivors)
        #pragma unroll
        for (int cb = 0; cb < 2; ++cb) {
            const int cc0 = wv * 8 + cb * 4;
            float4 b0[4], b1[4];
            #pragma unroll
            for (int q = 0; q < 4; ++q) {
                const float4* Bv = (const float4*)(B + (size_t)(c0 + cc0 + q) * ND);
                b0[q] = Bv[lane]; b1[q] = Bv[lane + 64];
            }
            for (int s = 0; s < gn; ++s) {     // gn-bounded: no padding work
                float4 a0v = *(const float4*)&Aload[s][lane * 4];
                float4 a1v = *(const float4*)&Aload[s][(lane + 64) * 4];
                float d0 = dot8(a0v, a1v, b0[0], b1[0]);
                float d1 = dot8(a0v, a1v, b0[1], b1[1]);
                float d2 = dot8(a0v, a1v, b0[2], b1[2]);
                float d3 = dot8(a0v, a1v, b0[3], b1[3]);
                #pragma unroll
                for (int off = 1; off < 64; off <<= 1) {
                    d0 += __shfl_xor(d0, off); d1 += __shfl_xor(d1, off);
                    d2 += __shfl_xor(d2, off); d3 += __shfl_xor(d3, off);
                }
                if (lane == 0) {
                    int aid = sAid[s];
                    float rn = sRn[s], dg = sDg[s], mg = sMg[s];
                    int lb = sLab[s];
                    float dv[4] = {d0, d1, d2, d3};
                    #pragma unroll
                    for (int q = 0; q < 4; ++q) {
                        int cc = cc0 + q;
                        if (colLab_s[cc] != lb) {
                            float lm = dv[q] * rn * colRn_s[cc] - dg + mg;
                            if (lm > 0.0f && lm < mg)
                                atomicMin(&negIdx[z * NB + aid], c0 + cc);
                        }
                    }
                }
            }
        }
    }
}

// Recompute winning sim value per straggler, block-reduce, accumulate.
__global__ __launch_bounds__(256) void final_k(
        const float* __restrict__ img, const float* __restrict__ txt,
        const float* __restrict__ cr,
        const float* rnImg, const float* rnTxt, const float* rnCr,
        const float* dgSim, const float* dgCr,
        const float* __restrict__ margin, const float* mgCr,
        const float* __restrict__ betap,
        const int* stragCnt, const int* stragList, const int* negIdx,
        float* out) {
    __shared__ float s4[4];
    const int tid = threadIdx.x, z = blockIdx.y;
    const float *A, *B, *rnA, *rnB, *dgA, *mgA;
    pass_arrays(z, img, txt, cr, rnImg, rnTxt, rnCr, dgSim, dgCr, margin, mgCr,
                A, B, rnA, rnB, dgA, mgA);
    int t = blockIdx.x * 256 + tid;
    float contrib = 0.0f;
    if (t < stragCnt[z]) {
        int a = stragList[z * NB + t];
        int idx = negIdx[z * NB + a];
        if (idx != INT_MAX) {
            const float4* Av = (const float4*)(A + (size_t)a   * ND);
            const float4* Bv = (const float4*)(B + (size_t)idx * ND);
            float d = 0.0f;
            #pragma unroll 8
            for (int i = 0; i < ND / 4; ++i) {
                float4 x = Av[i], y = Bv[i];
                d += x.x*y.x + x.y*y.y + x.z*y.z + x.w*y.w;
            }
            float lm = d * rnA[a] * rnB[idx] - dgA[a] + mgA[a];
            contrib = fmaxf(lm, 0.0f);
        }
    }
    #pragma unroll
    for (int off = 32; off; off >>= 1) contrib += __shfl_xor(contrib, off);
    if ((tid & 63) == 0) s4[tid >> 6] = contrib;
    __syncthreads();
    if (tid == 0) {
        float sum = s4[0] + s4[1] + s4[2] + s4[3];
        if (sum != 0.0f) atomicAdd(out, sum * ((z >= 2) ? betap[0] : 1.0f));
    }
}

// ===========================================================================
// Fallback path (no workspace) — the proven round-3 single-kernel version.
// ===========================================================================

__global__ __launch_bounds__(256) void zero_k(float* out, int n) {
    int g = blockIdx.x * 256 + threadIdx.x;
    if (g < n) out[g] = 0.0f;
}

template <int U>
__device__ void stragScan(const float* __restrict__ A, const float* __restrict__ B,
                          const int* __restrict__ labels, int a0, int u, int scol,
                          const int* sList, int g0,
                          const float* aRn, const float* aDg, const float* aMg,
                          const int* aLab, int* sMin8, int* doneMask,
                          float* blockAcc) {
    const int tid = threadIdx.x;
    float rn_s[U], dg_s[U], mg_s[U];
    int lab_s[U];
    const float4* Av[U];
    #pragma unroll
    for (int s = 0; s < U; ++s) {
        int slot = sList[g0 + (s < u ? s : 0)];
        rn_s[s] = aRn[slot]; dg_s[s] = aDg[slot]; mg_s[s] = aMg[slot];
        lab_s[s] = aLab[slot];
        Av[s] = (const float4*)(A + (size_t)(a0 + slot) * ND);
    }
    if (tid < U) sMin8[tid] = INT_MAX;
    if (tid == 0) *doneMask = 0;
    __syncthreads();
    for (int jb = scol; jb < NB; jb += 256) {
        int j = jb + tid;
        bool jv = (j < NB);
        int mask = *doneMask;
        float dot[U];
        #pragma unroll
        for (int s = 0; s < U; ++s) dot[s] = 0.0f;
        float ssq = 0.0f;
        if (jv) {
            const float4* Bv = (const float4*)(B + (size_t)j * ND);
            #pragma unroll 4
            for (int k4 = 0; k4 < ND / 4; ++k4) {
                float4 b = Bv[k4];
                ssq += b.x*b.x + b.y*b.y + b.z*b.z + b.w*b.w;
                #pragma unroll
                for (int s = 0; s < U; ++s) {
                    float4 a = Av[s][k4];
                    dot[s] += a.x*b.x + a.y*b.y + a.z*b.z + a.w*b.w;
                }
            }
        }
        float rnb = 1.0f / (sqrtf(ssq) + 1e-8f);
        int lj = jv ? labels[j] : -1;
        float lmv[U];
        #pragma unroll
        for (int s = 0; s < U; ++s) {
            lmv[s] = dot[s] * rn_s[s] * rnb - dg_s[s] + mg_s[s];
            if (jv && s < u && !((mask >> s) & 1) && lj != lab_s[s] &&
                lmv[s] > 0.0f && lmv[s] < mg_s[s])
                atomicMin(&sMin8[s], j);
        }
        __syncthreads();
        #pragma unroll
        for (int s = 0; s < U; ++s)
            if (jv && s < u && !((mask >> s) & 1) && sMin8[s] == j)
                atomicAdd(blockAcc, lmv[s]);
        __syncthreads();
        if (tid == 0) {
            int m2 = 0;
            for (int s = 0; s < u; ++s)
                if (sMin8[s] != INT_MAX) m2 |= (1 << s);
            *doneMask = m2;
        }
        __syncthreads();
        if (*doneMask == (1 << u) - 1) break;
    }
}

__global__ __launch_bounds__(256) void mine_k(const float* __restrict__ img,
                                              const float* __restrict__ txt,
                                              const float* __restrict__ cr,
                                              const int*   __restrict__ labels,
                                              const int*   __restrict__ flagp,
                                              const float* __restrict__ margin,
                                              const float* __restrict__ betap,
                                              float* __restrict__ out) {
    __shared__ __align__(16) float As[16][64];
    __shared__ __align__(16) float Bs[16][64];
    __shared__ float aRn[64], aDg[64], aMg[64];
    __shared__ int   aLab[64];
    __shared__ float colRn[64];
    __shared__ int   colLab[64];
    __shared__ int   resIdx[64], prevIdx[64];
    __shared__ int   cnt;
    __shared__ float blockAcc;
    __shared__ int   sList[64];
    __shared__ int   sCnt;
    __shared__ int   sMin8[8];
    __shared__ int   doneMask;

    const int tid  = threadIdx.x;
    const int z    = blockIdx.y;
    const int a0   = blockIdx.x * 64;
    const int flag = flagp[0];
    const float* A = (z == 1) ? txt : (z == 3) ? cr : img;
    const float* B = (z == 0) ? txt : (z == 2) ? cr : img;
    {
        int ar = tid >> 2, q = tid & 3;
        int a  = a0 + ar;
        const float4* iv = (const float4*)(img + (size_t)a * ND) + q * 32;
        const float4* tv = (const float4*)(txt + (size_t)a * ND) + q * 32;
        const float4* cv = (const float4*)(cr  + (size_t)a * ND) + q * 32;
        float sii = 0, stt = 0, scc = 0, sit = 0, sic = 0;
        #pragma unroll 4
        for (int i = 0; i < 32; ++i) {
            float4 x = iv[i], y = tv[i], w = cv[i];
            sii += x.x*x.x + x.y*x.y + x.z*x.z + x.w*x.w;
            stt += y.x*y.x + y.y*y.y + y.z*y.z + y.w*y.w;
            scc += w.x*w.x + w.y*w.y + w.z*w.z + w.w*w.w;
            sit += x.x*y.x + x.y*y.y + x.z*y.z + x.w*y.w;
            sic += x.x*w.x + x.y*w.y + x.z*w.z + x.w*w.w;
        }
        sii += __shfl_xor(sii, 1); sii += __shfl_xor(sii, 2);
        stt += __shfl_xor(stt, 1); stt += __shfl_xor(stt, 2);
        sit += __shfl_xor(sit, 1); sit += __shfl_xor(sit, 2);
        scc += __shfl_xor(scc, 1); scc += __shfl_xor(scc, 2);
        sic += __shfl_xor(sic, 1); sic += __shfl_xor(sic, 2);
        if (q == 0) {
            float rnI = 1.0f / (sqrtf(sii) + 1e-8f);
            float rnT = 1.0f / (sqrtf(stt) + 1e-8f);
            float ds  = sit * rnI * rnT;
            float m   = margin[a];
            float mg, rna, dgv;
            if (z >= 2) {
                float rnC = 1.0f / (sqrtf(scc) + 1e-8f);
                float dc  = sic * rnI * rnC;
                mg = flag ? (fminf(fabsf(dc) / fabsf(ds), 1.0f) + 1.0f) * m * 0.5f
                          : m * 0.5f;
                dgv = dc; rna = (z == 3) ? rnC : rnI;
            } else {
                mg = m; dgv = ds; rna = (z == 1) ? rnT : rnI;
            }
            aRn[ar] = rna; aDg[ar] = dgv; aMg[ar] = mg; aLab[ar] = labels[a];
            resIdx[ar] = (flag && mg < 0.16f) ? -1 : INT_MAX;
        }
        if (tid == 0) blockAcc = 0.0f;
    }
    __syncthreads();
    const int ty4  = (tid >> 4) * 4, tx4 = (tid & 15) * 4;
    const int lrow = tid >> 2,  lk4 = (tid & 3) * 4;
    int bandCols = 0, unresolved = 64;
    for (int jc = 0; jc < 2; ++jc) {
        int j0 = jc * 64;
        float acc[4][4];
        #pragma unroll
        for (int i = 0; i < 4; ++i)
            #pragma unroll
            for (int j = 0; j < 4; ++j) acc[i][j] = 0.0f;
        float bssq = 0.0f;
        for (int kc = 0; kc < ND; kc += 16) {
            __syncthreads();
            float4 va = *(const float4*)(A + (size_t)(a0 + lrow) * ND + kc + lk4);
            float4 vb = *(const float4*)(B + (size_t)(j0 + lrow) * ND + kc + lk4);
            As[lk4 + 0][lrow] = va.x; As[lk4 + 1][lrow] = va.y;
            As[lk4 + 2][lrow] = va.z; As[lk4 + 3][lrow] = va.w;
            Bs[lk4 + 0][lrow] = vb.x; Bs[lk4 + 1][lrow] = vb.y;
            Bs[lk4 + 2][lrow] = vb.z; Bs[lk4 + 3][lrow] = vb.w;
            bssq += vb.x*vb.x + vb.y*vb.y + vb.z*vb.z + vb.w*vb.w;
            __syncthreads();
            #pragma unroll
            for (int k = 0; k < 16; ++k) {
                float4 av = *(const float4*)&As[k][ty4];
                float4 bv = *(const float4*)&Bs[k][tx4];
                float ar[4] = {av.x, av.y, av.z, av.w};
                float br[4] = {bv.x, bv.y, bv.z, bv.w};
                #pragma unroll
                for (int i = 0; i < 4; ++i)
                    #pragma unroll
                    for (int j = 0; j < 4; ++j)
                        acc[i][j] = fmaf(ar[i], br[j], acc[i][j]);
            }
        }
        bssq += __shfl_xor(bssq, 1); bssq += __shfl_xor(bssq, 2);
        __syncthreads();
        if ((tid & 3) == 0) {
            colRn[lrow]  = 1.0f / (sqrtf(bssq) + 1e-8f);
            colLab[lrow] = labels[j0 + lrow];
        }
        if (tid < 64) prevIdx[tid] = resIdx[tid];
        __syncthreads();
        #pragma unroll
        for (int i = 0; i < 4; ++i) {
            int r = ty4 + i;
            if (prevIdx[r] != INT_MAX) continue;
            float dg = aDg[r], mgv = aMg[r], rna = aRn[r];
            int la = aLab[r];
            #pragma unroll
            for (int j = 0; j < 4; ++j) {
                int c = tx4 + j;
                if (colLab[c] == la) continue;
                float v  = acc[i][j] * rna * colRn[c];
                float lm = v - dg + mgv;
                if (lm > 0.0f && lm < mgv) atomicMin(&resIdx[r], j0 + c);
            }
        }
        __syncthreads();
        #pragma unroll
        for (int i = 0; i < 4; ++i) {
            int r = ty4 + i;
            if (prevIdx[r] != INT_MAX) continue;
            int w = resIdx[r];
            if (w == INT_MAX) continue;
            int c = w - j0 - tx4;
            if (c < 0 || c > 3) continue;
            float v  = acc[i][c] * aRn[r] * colRn[tx4 + c];
            float lm = v - aDg[r] + aMg[r];
            atomicAdd(&blockAcc, lm);
        }
        __syncthreads();
        if (tid == 0) cnt = 0;
        __syncthreads();
        if (tid < 64 && resIdx[tid] == INT_MAX) atomicAdd(&cnt, 1);
        __syncthreads();
        unresolved = cnt;
        bandCols = j0 + 64;
        __syncthreads();
        if (unresolved <= 8) break;
    }
    if (unresolved > 0) {
        if (tid == 0) sCnt = 0;
        __syncthreads();
        if (tid < 64 && resIdx[tid] == INT_MAX) {
            int pos = atomicAdd(&sCnt, 1);
            sList[pos] = tid;
        }
        __syncthreads();
        int total = sCnt;
        for (int g0 = 0; g0 < total; g0 += 8) {
            int u = min(8, total - g0);
            if (u == 1)      stragScan<1>(A, B, labels, a0, u, bandCols, sList, g0, aRn, aDg, aMg, aLab, sMin8, &doneMask, &blockAcc);
            else if (u == 2) stragScan<2>(A, B, labels, a0, u, bandCols, sList, g0, aRn, aDg, aMg, aLab, sMin8, &doneMask, &blockAcc);
            else if (u <= 4) stragScan<4>(A, B, labels, a0, u, bandCols, sList, g0, aRn, aDg, aMg, aLab, sMin8, &doneMask, &blockAcc);
            else             stragScan<8>(A, B, labels, a0, u, bandCols, sList, g0, aRn, aDg, aMg, aLab, sMin8, &doneMask, &blockAcc);
            __syncthreads();
        }
    }
    if (tid == 0 && blockAcc != 0.0f) {
        float scale = (z >= 2) ? betap[0] : 1.0f;
        atomicAdd(out, blockAcc * scale);
    }
}

// ===========================================================================

extern "C" void kernel_launch(void* const* d_in, const int* in_sizes, int n_in,
                              void* d_out, int out_size, void* d_ws, size_t ws_size,
                              hipStream_t stream) {
    const float* img    = (const float*)d_in[0];
    const float* txt    = (const float*)d_in[1];
    const float* cr     = (const float*)d_in[2];
    const int*   labels = (const int*)  d_in[3];
    const int*   flagp  = (const int*)  d_in[4];
    const float* marg   = (const float*)d_in[5];
    const float* betap  = (const float*)d_in[6];
    float* out = (float*)d_out;
    (void)in_sizes; (void)n_in;

    const size_t REQ = (size_t)(6 * NB) * 4 + (size_t)(4 * NB) * 4 + 64 +
                       (size_t)(4 * NB) * 4;
    if (ws_size >= REQ) {
        float* wf = (float*)d_ws;
        float* rnImg = wf + 0 * NB;
        float* rnTxt = wf + 1 * NB;
        float* rnCr  = wf + 2 * NB;
        float* dgSim = wf + 3 * NB;
        float* dgCr  = wf + 4 * NB;
        float* mgCr  = wf + 5 * NB;
        int* negIdx    = (int*)(wf + 6 * NB);
        int* stragCnt  = negIdx + 4 * NB;
        int* stragList = stragCnt + 16;

        stats_k<<<dim3(NB / 16),              dim3(256), 0, stream>>>(
            img, txt, cr, marg, flagp,
            rnImg, rnTxt, rnCr, dgSim, dgCr, mgCr, negIdx, stragCnt, out);
        band_k <<<dim3(NB / 64, 4),           dim3(256), 0, stream>>>(
            img, txt, cr, labels, flagp, marg, betap,
            rnImg, rnTxt, rnCr, dgSim, dgCr, mgCr, stragCnt, stragList, out);
        wina_k <<<dim3(WCHUNKS * WTILES, 4),  dim3(256), 0, stream>>>(
            img, txt, cr, labels, marg,
            rnImg, rnTxt, rnCr, dgSim, dgCr, mgCr,
            stragCnt, stragList, negIdx);
        tail_k <<<dim3(TCHUNKS, 4),           dim3(256), 0, stream>>>(
            img, txt, cr, labels, marg,
            rnImg, rnTxt, rnCr, dgSim, dgCr, mgCr,
            stragCnt, stragList, negIdx);
        final_k<<<dim3(NB / 256, 4),          dim3(256), 0, stream>>>(
            img, txt, cr, rnImg, rnTxt, rnCr, dgSim, dgCr, marg, mgCr, betap,
            stragCnt, stragList, negIdx, out);
    } else {
        zero_k<<<dim3((out_size + 255) / 256), dim3(256), 0, stream>>>(out, out_size);
        mine_k<<<dim3(NB / 64, 4), dim3(256), 0, stream>>>(img, txt, cr, labels,
                                                           flagp, marg, betap, out);
    }
}